// Round 1
// baseline (3348.877 us; speedup 1.0000x reference)
//
#include <hip/hip_runtime.h>
#include <cstdio>
#include <cmath>

typedef __attribute__((ext_vector_type(8))) short bf16x8;
typedef __attribute__((ext_vector_type(4))) float f32x4;

#define MFMA16(a, b, c) __builtin_amdgcn_mfma_f32_16x16x32_bf16((a), (b), (c), 0, 0, 0)

// ---------------- workspace layout (byte offsets) ----------------
#define WSO_PE    0u                          // float[128*128]
#define WSO_WQP   65536u                      // bf16 [256][256]
#define WSO_WKP   (WSO_WQP + 131072u)         // bf16 [256][512]
#define WSO_WVP   (WSO_WKP + 262144u)         // bf16 [256][256]
#define WSO_WSP   (WSO_WVP + 131072u)         // bf16 [256][256]
#define WSO_WIN   (WSO_WSP + 131072u)         // bf16 [768][256] (Wq|Wk|Wv)
#define WSO_WOP   (WSO_WIN + 393216u)         // bf16 [256][256]
#define WSO_WC    (WSO_WOP + 131072u)         // bf16 [9][256][512]
#define WSO_YT    (WSO_WC + 2359296u)         // bf16 [8][128][128][512]  (NHWC conv input)
#define WSO_SUMS  (WSO_YT + 134217728u)       // float[512] (sum | sumsq)
#define WSO_SC    (WSO_SUMS + 2048u)          // float[512] (scale | shift)
#define WSO_TOTAL (WSO_SC + 2048u)

#define SMEM_ATTN 147456
#define SMEM_CONV 41472

__device__ __forceinline__ unsigned short f2b(float x) {
  unsigned int u = __builtin_bit_cast(unsigned int, x);
  u += 0x7fffu + ((u >> 16) & 1u);
  return (unsigned short)(u >> 16);
}

// swizzled LDS 8-element bf16 read; same swizzle used by every LDS writer
__device__ __forceinline__ bf16x8 rd8(const unsigned short* s, int row, int stride, int k) {
  return *reinterpret_cast<const bf16x8*>(s + row * stride + (k ^ ((row & 7) << 3)));
}

// ================= prep: pe table + all weight conversions =================
__global__ void k_prep(const float* __restrict__ qp, const float* __restrict__ kp,
                       const float* __restrict__ vp, const float* __restrict__ spw,
                       const float* __restrict__ inw, const float* __restrict__ opw,
                       const float* __restrict__ postw,
                       float* __restrict__ peT, unsigned short* __restrict__ wdst) {
  unsigned id = blockIdx.x * 256u + threadIdx.x;
  if (id < 16384u) {
    int p = id >> 7, j = id & 127;
    float div = expf(-9.210340371976184f * (float)(j & ~1) * (1.0f / 128.0f));
    float ang = (float)p * div;
    peT[id] = (j & 1) ? cosf(ang) : sinf(ang);
    return;
  }
  unsigned i = id - 16384u;
  if (i >= 1769472u) return;
  float v;
  if (i < 65536u)            v = qp[i];
  else if (i < 196608u)      v = kp[i - 65536u];
  else if (i < 262144u)      v = vp[i - 196608u];
  else if (i < 327680u)      v = spw[i - 262144u];
  else if (i < 524288u)      v = inw[i - 327680u];
  else if (i < 589824u)      v = opw[i - 524288u];
  else {
    unsigned r = i - 589824u;
    unsigned t = r >> 17;              // tap = ky*3+kx
    unsigned q = r & 131071u;
    unsigned o = q >> 9, ic = q & 511u;
    v = postw[(o * 512u + ic) * 9u + t];
  }
  wdst[i] = f2b(v);
}

// ================= shared GEMM: OUT[e][tok] += W[e][c] * X[tok][c] =================
// A = weights (global, row-major [256][Kw], M = e), B = tokens (LDS, [64][strideB], swizzled)
__device__ __forceinline__ void gemm4x4(f32x4 acc[4][4], const unsigned short* __restrict__ wA,
                                        int Kw, int kw0, const unsigned short* sB, int strideB,
                                        int nK, int wid, int lane) {
  const int rA = lane & 15;
  const int kq = (lane >> 4) << 3;
  for (int ks = 0; ks < nK; ks += 32) {
    bf16x8 a[4];
#pragma unroll
    for (int rt = 0; rt < 4; ++rt)
      a[rt] = *reinterpret_cast<const bf16x8*>(wA + (wid * 64 + rt * 16 + rA) * Kw + kw0 + ks + kq);
#pragma unroll
    for (int ct = 0; ct < 4; ++ct) {
      bf16x8 bb = rd8(sB, ct * 16 + rA, strideB, ks + kq);
#pragma unroll
      for (int rt = 0; rt < 4; ++rt) acc[rt][ct] = MFMA16(a[rt], bb, acc[rt][ct]);
    }
  }
}

// stage 64 tokens x 128 channels of an NCHW fp32 input into swizzled bf16 LDS
__device__ __forceinline__ void stage128(unsigned short* sB, const float* __restrict__ src,
                                         int b, int Cin, int c0, int h0, int w0, int tid) {
#pragma unroll
  for (int it = 0; it < 4; ++it) {
    int p = tid + (it << 8);
    int c = p >> 3, r = p & 7;
    const float* g = src + ((long)(b * Cin + c0 + c) * 128 + (h0 + r)) * 128 + w0;
    float4 f0 = *reinterpret_cast<const float4*>(g);
    float4 f1 = *reinterpret_cast<const float4*>(g + 4);
    float v[8] = {f0.x, f0.y, f0.z, f0.w, f1.x, f1.y, f1.z, f1.w};
#pragma unroll
    for (int i = 0; i < 8; ++i) {
      int tok = (r << 3) + i;
      sB[tok * 128 + (c ^ ((tok & 7) << 3))] = f2b(v[i]);
    }
  }
}

__device__ __forceinline__ void epi_pe_lds(unsigned short* buf, const f32x4 acc[4][4],
                                           const float* peL, int wid, int lane) {
#pragma unroll
  for (int rt = 0; rt < 4; ++rt) {
    int e0 = wid * 64 + rt * 16 + ((lane >> 4) << 2);
#pragma unroll
    for (int ct = 0; ct < 4; ++ct) {
      int tok = ct * 16 + (lane & 15);
      int r = tok >> 3, cpx = tok & 7;
      const float* pe = (e0 < 128) ? (peL + r * 128 + e0) : (peL + (8 + cpx) * 128 + (e0 - 128));
      ushort4 pk;
      pk.x = f2b(acc[rt][ct][0] + pe[0]);
      pk.y = f2b(acc[rt][ct][1] + pe[1]);
      pk.z = f2b(acc[rt][ct][2] + pe[2]);
      pk.w = f2b(acc[rt][ct][3] + pe[3]);
      *reinterpret_cast<ushort4*>(buf + tok * 256 + (e0 ^ ((tok & 7) << 3))) = pk;
    }
  }
}

__device__ __forceinline__ void epi_bias_lds(unsigned short* buf, const f32x4 acc[4][4],
                                             const float* __restrict__ bias, int wid, int lane) {
#pragma unroll
  for (int rt = 0; rt < 4; ++rt) {
    int e0 = wid * 64 + rt * 16 + ((lane >> 4) << 2);
    float4 bs = *reinterpret_cast<const float4*>(bias + e0);
#pragma unroll
    for (int ct = 0; ct < 4; ++ct) {
      int tok = ct * 16 + (lane & 15);
      ushort4 pk;
      pk.x = f2b(acc[rt][ct][0] + bs.x);
      pk.y = f2b(acc[rt][ct][1] + bs.y);
      pk.z = f2b(acc[rt][ct][2] + bs.z);
      pk.w = f2b(acc[rt][ct][3] + bs.w);
      *reinterpret_cast<ushort4*>(buf + tok * 256 + (e0 ^ ((tok & 7) << 3))) = pk;
    }
  }
}

__device__ __forceinline__ void epi_global(unsigned short* __restrict__ y_t, const f32x4 acc[4][4],
                                           const float* __restrict__ bias, int chOff,
                                           int b, int h0, int w0, int wid, int lane) {
#pragma unroll
  for (int rt = 0; rt < 4; ++rt) {
    int e0 = wid * 64 + rt * 16 + ((lane >> 4) << 2);
    float4 bs = bias ? *reinterpret_cast<const float4*>(bias + e0) : make_float4(0.f, 0.f, 0.f, 0.f);
#pragma unroll
    for (int ct = 0; ct < 4; ++ct) {
      int tok = ct * 16 + (lane & 15);
      int r = tok >> 3, cpx = tok & 7;
      long gy = (((long)(b * 128 + h0 + r)) * 128 + (w0 + cpx)) * 512 + chOff + e0;
      ushort4 pk;
      pk.x = f2b(acc[rt][ct][0] + bs.x);
      pk.y = f2b(acc[rt][ct][1] + bs.y);
      pk.z = f2b(acc[rt][ct][2] + bs.z);
      pk.w = f2b(acc[rt][ct][3] + bs.w);
      *reinterpret_cast<ushort4*>(y_t + gy) = pk;
    }
  }
}

// ================= fused: projections + PE + window MHA + out-proj + skip =================
__launch_bounds__(256, 1)
__global__ void k_attn(const float* __restrict__ x5, const float* __restrict__ d1,
                       const float* __restrict__ d2,
                       const unsigned short* __restrict__ w_qp, const unsigned short* __restrict__ w_kp,
                       const unsigned short* __restrict__ w_vp, const unsigned short* __restrict__ w_sp,
                       const unsigned short* __restrict__ w_in, const unsigned short* __restrict__ w_op,
                       const float* __restrict__ in_b, const float* __restrict__ out_b,
                       const float* __restrict__ peT, unsigned short* __restrict__ y_t) {
  extern __shared__ unsigned short sm[];
  unsigned short* bufQ = sm;              // [64][256]  q -> qh
  unsigned short* bufK = sm + 16384;      // [64][256]  k -> kh
  unsigned short* bufV = sm + 32768;      // [64][256]  v -> o
  unsigned short* bufX = sm + 49152;      // peL (float[16][128]) then vhT [256][64]
  unsigned short* bufI = sm + 65536;      // [64][128] staging; later P [64][64]
  float* peL = reinterpret_cast<float*>(bufX);

  const int tid = threadIdx.x;
  const int lane = tid & 63;
  const int wid = tid >> 6;
  const int kq = (lane >> 4) << 3;
  const int win = blockIdx.x;
  const int b = win >> 8, wh = (win >> 4) & 15, ww = win & 15;
  const int h0 = wh * 8, w0 = ww * 8;

  // stage pe rows for this window: rows 0-7 = peT[h0+r], rows 8-15 = peT[w0+c]
  for (int i = tid; i < 2048; i += 256) {
    int rr = i >> 7, e = i & 127;
    int p = (rr < 8) ? (h0 + rr) : (w0 + rr - 8);
    peL[i] = peT[p * 128 + e];
  }

  const f32x4 vz = {0.f, 0.f, 0.f, 0.f};
  f32x4 accA[4][4], accB[4][4];

  // ---- q & skip (from d1) ----
#pragma unroll
  for (int i = 0; i < 4; ++i)
#pragma unroll
    for (int j = 0; j < 4; ++j) { accA[i][j] = vz; accB[i][j] = vz; }
  for (int c0 = 0; c0 < 256; c0 += 128) {
    __syncthreads();
    stage128(bufI, d1, b, 256, c0, h0, w0, tid);
    __syncthreads();
    gemm4x4(accA, w_qp, 256, c0, bufI, 128, 128, wid, lane);
    gemm4x4(accB, w_sp, 256, c0, bufI, 128, 128, wid, lane);
  }
  epi_pe_lds(bufQ, accA, peL, wid, lane);
  epi_global(y_t, accB, nullptr, 256, b, h0, w0, wid, lane);   // skip -> channels 256..511

  // ---- k (from x5, K=512) ----
#pragma unroll
  for (int i = 0; i < 4; ++i)
#pragma unroll
    for (int j = 0; j < 4; ++j) accA[i][j] = vz;
  for (int c0 = 0; c0 < 512; c0 += 128) {
    __syncthreads();
    stage128(bufI, x5, b, 512, c0, h0, w0, tid);
    __syncthreads();
    gemm4x4(accA, w_kp, 512, c0, bufI, 128, 128, wid, lane);
  }
  epi_pe_lds(bufK, accA, peL, wid, lane);

  // ---- v (from d2) ----
#pragma unroll
  for (int i = 0; i < 4; ++i)
#pragma unroll
    for (int j = 0; j < 4; ++j) accA[i][j] = vz;
  for (int c0 = 0; c0 < 256; c0 += 128) {
    __syncthreads();
    stage128(bufI, d2, b, 256, c0, h0, w0, tid);
    __syncthreads();
    gemm4x4(accA, w_vp, 256, c0, bufI, 128, 128, wid, lane);
  }
  epi_pe_lds(bufV, accA, peL, wid, lane);

  __syncthreads();   // all of bufQ/K/V complete (cross-wave columns)

  // ---- qh = q @ Wq^T + bq (in place) ----
#pragma unroll
  for (int i = 0; i < 4; ++i)
#pragma unroll
    for (int j = 0; j < 4; ++j) accA[i][j] = vz;
  gemm4x4(accA, w_in, 256, 0, bufQ, 256, 256, wid, lane);
  __syncthreads();
  epi_bias_lds(bufQ, accA, in_b, wid, lane);

  // ---- kh ----
#pragma unroll
  for (int i = 0; i < 4; ++i)
#pragma unroll
    for (int j = 0; j < 4; ++j) accA[i][j] = vz;
  gemm4x4(accA, w_in + 65536, 256, 0, bufK, 256, 256, wid, lane);
  __syncthreads();
  epi_bias_lds(bufK, accA, in_b + 256, wid, lane);

  // ---- vh -> transposed vhT [ch][tok] in bufX (pe dead) ----
#pragma unroll
  for (int i = 0; i < 4; ++i)
#pragma unroll
    for (int j = 0; j < 4; ++j) accA[i][j] = vz;
  gemm4x4(accA, w_in + 131072, 256, 0, bufV, 256, 256, wid, lane);
  __syncthreads();
  {
    unsigned short* vhT = bufX;
#pragma unroll
    for (int rt = 0; rt < 4; ++rt) {
      int e0 = wid * 64 + rt * 16 + ((lane >> 4) << 2);
      float4 bs = *reinterpret_cast<const float4*>(in_b + 512 + e0);
      float bsv[4] = {bs.x, bs.y, bs.z, bs.w};
#pragma unroll
      for (int ct = 0; ct < 4; ++ct) {
        int tok = ct * 16 + (lane & 15);
#pragma unroll
        for (int j = 0; j < 4; ++j) {
          int ch = e0 + j;
          vhT[ch * 64 + (tok ^ ((ch & 7) << 3))] = f2b(accA[rt][ct][j] + bsv[j]);
        }
      }
    }
  }
  __syncthreads();   // qh/kh/vhT visible; bufV free for o

  // ---- per-head attention; o accumulates into bufV ----
  unsigned short* Pb = bufI;               // [64][64], stride 64
  unsigned short* vhT = bufX;
  const float scl = 0.17677669529663687f;  // 1/sqrt(32)
  for (int hd = 0; hd < 8; ++hd) {
    // scores: wave owns q rows wid*16..+15, all 64 key tokens
    f32x4 sv[4];
#pragma unroll
    for (int ct = 0; ct < 4; ++ct) sv[ct] = vz;
    {
      bf16x8 aq = rd8(bufQ, wid * 16 + (lane & 15), 256, hd * 32 + kq);
#pragma unroll
      for (int ct = 0; ct < 4; ++ct) {
        bf16x8 bk = rd8(bufK, ct * 16 + (lane & 15), 256, hd * 32 + kq);
        sv[ct] = MFMA16(aq, bk, sv[ct]);
      }
    }
    // softmax over 64 cols per q-row (rows = (lane>>4)*4+j, cols = lane&15 + 16*ct)
    float pr[4][4];
#pragma unroll
    for (int j = 0; j < 4; ++j) {
      float mx = fmaxf(fmaxf(sv[0][j], sv[1][j]), fmaxf(sv[2][j], sv[3][j])) * scl;
#pragma unroll
      for (int m = 8; m >= 1; m >>= 1) mx = fmaxf(mx, __shfl_xor(mx, m));
      float sum = 0.f;
#pragma unroll
      for (int ct = 0; ct < 4; ++ct) {
        float p = __expf(sv[ct][j] * scl - mx);
        pr[ct][j] = p;
        sum += p;
      }
#pragma unroll
      for (int m = 8; m >= 1; m >>= 1) sum += __shfl_xor(sum, m);
      float inv = 1.f / sum;
#pragma unroll
      for (int ct = 0; ct < 4; ++ct) pr[ct][j] *= inv;
    }
    // store P (bf16) — per-wave-private rows, no barrier needed
#pragma unroll
    for (int ct = 0; ct < 4; ++ct)
#pragma unroll
      for (int j = 0; j < 4; ++j) {
        int q = wid * 16 + ((lane >> 4) << 2) + j;
        int kt = ct * 16 + (lane & 15);
        Pb[q * 64 + (kt ^ ((q & 7) << 3))] = f2b(pr[ct][j]);
      }
    // PV: OUT[ch][q] = sum_k vhT[ch][k] * P[q][k]
    f32x4 ov[2];
    ov[0] = vz; ov[1] = vz;
#pragma unroll
    for (int ks = 0; ks < 64; ks += 32) {
      bf16x8 bp = rd8(Pb, wid * 16 + (lane & 15), 64, ks + kq);
#pragma unroll
      for (int rt = 0; rt < 2; ++rt) {
        bf16x8 av = rd8(vhT, hd * 32 + rt * 16 + (lane & 15), 64, ks + kq);
        ov[rt] = MFMA16(av, bp, ov[rt]);
      }
    }
    // o epilogue: rows=ch, cols=tok -> bufV[tok][ch]
#pragma unroll
    for (int rt = 0; rt < 2; ++rt) {
      int ch0 = hd * 32 + rt * 16 + ((lane >> 4) << 2);
      int tok = wid * 16 + (lane & 15);
      ushort4 pk;
      pk.x = f2b(ov[rt][0]);
      pk.y = f2b(ov[rt][1]);
      pk.z = f2b(ov[rt][2]);
      pk.w = f2b(ov[rt][3]);
      *reinterpret_cast<ushort4*>(bufV + tok * 256 + (ch0 ^ ((tok & 7) << 3))) = pk;
    }
  }
  __syncthreads();

  // ---- out projection -> y_t channels 0..255 ----
#pragma unroll
  for (int i = 0; i < 4; ++i)
#pragma unroll
    for (int j = 0; j < 4; ++j) accA[i][j] = vz;
  gemm4x4(accA, w_op, 256, 0, bufV, 256, 256, wid, lane);
  epi_global(y_t, accA, out_b, 0, b, h0, w0, wid, lane);
}

// ================= conv 3x3 (512->256) implicit GEMM, NHWC bf16 in, NCHW fp32 out =================
__launch_bounds__(512, 1)
__global__ void k_conv(const unsigned short* __restrict__ y_t, const unsigned short* __restrict__ wc,
                       float* __restrict__ out) {
  extern __shared__ unsigned short sp_[];   // patch [324][64] swizzled
  const int tid = threadIdx.x, lane = tid & 63, wid = tid >> 6;
  const int kq = (lane >> 4) << 3;
  const int bi = blockIdx.x;
  const int b = bi >> 6, t = bi & 63, ty = t >> 3, tx = t & 7;
  const int h0 = ty * 16, w0 = tx * 16;

  const f32x4 vz = {0.f, 0.f, 0.f, 0.f};
  f32x4 acc[2][16];
#pragma unroll
  for (int rt = 0; rt < 2; ++rt)
#pragma unroll
    for (int ct = 0; ct < 16; ++ct) acc[rt][ct] = vz;

  for (int cc = 0; cc < 8; ++cc) {
    const int c0 = cc * 64;
    __syncthreads();
    for (int i = tid; i < 2592; i += 512) {
      int pidx = i >> 3, cu = (i & 7) << 3;
      int pr = pidx / 18, pc = pidx - pr * 18;
      int hh = h0 + pr - 1, wp = w0 + pc - 1;
      uint4 val = make_uint4(0u, 0u, 0u, 0u);
      if ((unsigned)hh < 128u && (unsigned)wp < 128u)
        val = *reinterpret_cast<const uint4*>(y_t + (((long)(b * 128 + hh)) * 128 + wp) * 512 + c0 + cu);
      *reinterpret_cast<uint4*>(sp_ + pidx * 64 + (cu ^ ((pidx & 7) << 3))) = val;
    }
    __syncthreads();
#pragma unroll
    for (int ky = 0; ky < 3; ++ky)
#pragma unroll
      for (int kx = 0; kx < 3; ++kx) {
        const unsigned short* wt = wc + (ky * 3 + kx) * 131072;
#pragma unroll
        for (int ks = 0; ks < 64; ks += 32) {
          bf16x8 a0 = *reinterpret_cast<const bf16x8*>(wt + (wid * 32 + (lane & 15)) * 512 + c0 + ks + kq);
          bf16x8 a1 = *reinterpret_cast<const bf16x8*>(wt + (wid * 32 + 16 + (lane & 15)) * 512 + c0 + ks + kq);
#pragma unroll
          for (int ct = 0; ct < 16; ++ct) {
            int prow = (ct + ky) * 18 + (lane & 15) + kx;
            bf16x8 bb = rd8(sp_, prow, 64, ks + kq);
            acc[0][ct] = MFMA16(a0, bb, acc[0][ct]);
            acc[1][ct] = MFMA16(a1, bb, acc[1][ct]);
          }
        }
      }
  }
  // epilogue: rows = oc, cols = px
#pragma unroll
  for (int rt = 0; rt < 2; ++rt) {
    int oc0 = wid * 32 + rt * 16 + ((lane >> 4) << 2);
#pragma unroll
    for (int ct = 0; ct < 16; ++ct) {
      int hh = h0 + ct, wp = w0 + (lane & 15);
      long base = (((long)(b * 256 + oc0)) * 128 + hh) * 128 + wp;
#pragma unroll
      for (int j = 0; j < 4; ++j) out[base + (long)j * 16384] = acc[rt][ct][j];
    }
  }
}

// ================= BN stats / finalize / apply =================
__global__ void k_stats(const float* __restrict__ out, float* __restrict__ sums) {
  __shared__ float s1[256], s2[256];
  int c = blockIdx.x, tid = threadIdx.x;
  float a1 = 0.f, a2 = 0.f;
  for (int bb = 0; bb < 8; ++bb) {
    const float* p = out + ((long)(bb * 256 + c)) * 16384;
    for (int i = tid; i < 16384; i += 256) { float v = p[i]; a1 += v; a2 += v * v; }
  }
  s1[tid] = a1; s2[tid] = a2;
  __syncthreads();
  for (int s = 128; s > 0; s >>= 1) {
    if (tid < s) { s1[tid] += s1[tid + s]; s2[tid] += s2[tid + s]; }
    __syncthreads();
  }
  if (tid == 0) { sums[c] = s1[0]; sums[256 + c] = s2[0]; }
}

__global__ void k_final(const float* __restrict__ sums, const float* __restrict__ gamma,
                        const float* __restrict__ beta, float* __restrict__ sc) {
  int c = threadIdx.x;
  float mean = sums[c] * (1.f / 131072.f);
  float var = sums[256 + c] * (1.f / 131072.f) - mean * mean;
  float s = gamma[c] * rsqrtf(var + 1e-5f);
  sc[c] = s;
  sc[256 + c] = beta[c] - mean * s;
}

__global__ void k_apply(float* __restrict__ out, const float* __restrict__ sc) {
  const long n4 = 33554432 / 4;
  for (long i4 = (long)blockIdx.x * 256 + threadIdx.x; i4 < n4; i4 += (long)gridDim.x * 256) {
    float4 v = reinterpret_cast<float4*>(out)[i4];
    int c = (int)((i4 >> 12) & 255);
    float s = sc[c], sh = sc[256 + c];
    v.x = fmaxf(v.x * s + sh, 0.f);
    v.y = fmaxf(v.y * s + sh, 0.f);
    v.z = fmaxf(v.z * s + sh, 0.f);
    v.w = fmaxf(v.w * s + sh, 0.f);
    reinterpret_cast<float4*>(out)[i4] = v;
  }
}

// ================= launch =================
extern "C" void kernel_launch(void* const* d_in, const int* in_sizes, int n_in,
                              void* d_out, int out_size, void* d_ws, size_t ws_size,
                              hipStream_t stream) {
  const float* x5 = (const float*)d_in[0];
  const float* d1 = (const float*)d_in[1];
  const float* d2 = (const float*)d_in[2];
  const float* kp = (const float*)d_in[3];
  const float* qp = (const float*)d_in[4];
  const float* vp = (const float*)d_in[5];
  const float* spw = (const float*)d_in[6];
  const float* inw = (const float*)d_in[7];
  const float* inb = (const float*)d_in[8];
  const float* opw = (const float*)d_in[9];
  const float* opb = (const float*)d_in[10];
  const float* pw = (const float*)d_in[11];
  const float* gamma = (const float*)d_in[12];
  const float* beta = (const float*)d_in[13];

  if (ws_size < (size_t)WSO_TOTAL) {
    fprintf(stderr, "kernel_launch: ws too small: %zu < %u\n", ws_size, WSO_TOTAL);
    return;
  }

  char* ws = (char*)d_ws;
  float* peT = (float*)(ws + WSO_PE);
  unsigned short* w_qp = (unsigned short*)(ws + WSO_WQP);
  unsigned short* w_kp = (unsigned short*)(ws + WSO_WKP);
  unsigned short* w_vp = (unsigned short*)(ws + WSO_WVP);
  unsigned short* w_sp = (unsigned short*)(ws + WSO_WSP);
  unsigned short* w_in = (unsigned short*)(ws + WSO_WIN);
  unsigned short* w_op = (unsigned short*)(ws + WSO_WOP);
  unsigned short* w_c = (unsigned short*)(ws + WSO_WC);
  unsigned short* y_t = (unsigned short*)(ws + WSO_YT);
  float* sums = (float*)(ws + WSO_SUMS);
  float* sc = (float*)(ws + WSO_SC);

  hipFuncSetAttribute(reinterpret_cast<const void*>(k_attn),
                      hipFuncAttributeMaxDynamicSharedMemorySize, SMEM_ATTN);

  k_prep<<<6976, 256, 0, stream>>>(qp, kp, vp, spw, inw, opw, pw, peT, w_qp);
  k_attn<<<2048, 256, SMEM_ATTN, stream>>>(x5, d1, d2, w_qp, w_kp, w_vp, w_sp, w_in, w_op,
                                           inb, opb, peT, y_t);
  k_conv<<<512, 512, SMEM_CONV, stream>>>(y_t, w_c, (float*)d_out);
  k_stats<<<256, 256, 0, stream>>>((const float*)d_out, sums);
  k_final<<<1, 256, 0, stream>>>(sums, gamma, beta, sc);
  k_apply<<<2048, 256, 0, stream>>>((float*)d_out, sc);
}

// Round 2
// 2504.367 us; speedup vs baseline: 1.3372x; 1.3372x over previous
//
#include <hip/hip_runtime.h>
#include <cstdio>
#include <cmath>

typedef __attribute__((ext_vector_type(8))) short bf16x8;
typedef __attribute__((ext_vector_type(4))) float f32x4;

#define MFMA16(a, b, c) __builtin_amdgcn_mfma_f32_16x16x32_bf16((a), (b), (c), 0, 0, 0)

// ---------------- workspace layout (byte offsets) ----------------
#define WSO_PE    0u                          // float[128*128]
#define WSO_WQP   65536u                      // bf16 [256][256]
#define WSO_WKP   (WSO_WQP + 131072u)         // bf16 [256][512]
#define WSO_WVP   (WSO_WKP + 262144u)         // bf16 [256][256]
#define WSO_WSP   (WSO_WVP + 131072u)         // bf16 [256][256]
#define WSO_WIN   (WSO_WSP + 131072u)         // bf16 [768][256] (Wq|Wk|Wv)
#define WSO_WOP   (WSO_WIN + 393216u)         // bf16 [256][256]
#define WSO_WC    (WSO_WOP + 131072u)         // bf16 [9][16][8][2][512] fragment-packed
#define WSO_YT    (WSO_WC + 2359296u)         // bf16 [8][16cc][128][128][32c]  (conv input)
#define WSO_SUMS  (WSO_YT + 134217728u)       // float[512] (sum | sumsq)
#define WSO_SC    (WSO_SUMS + 2048u)          // float[512] (scale | shift)
#define WSO_TOTAL (WSO_SC + 2048u)

#define SMEM_ATTN 147456

__device__ __forceinline__ unsigned short f2b(float x) {
  unsigned int u = __builtin_bit_cast(unsigned int, x);
  u += 0x7fffu + ((u >> 16) & 1u);
  return (unsigned short)(u >> 16);
}

// swizzled LDS 8-element bf16 read; same swizzle used by every LDS writer (256/128-stride bufs)
__device__ __forceinline__ bf16x8 rd8(const unsigned short* s, int row, int stride, int k) {
  return *reinterpret_cast<const bf16x8*>(s + row * stride + (k ^ ((row & 7) << 3)));
}

// ================= prep: pe table + all weight conversions =================
__global__ void k_prep(const float* __restrict__ qp, const float* __restrict__ kp,
                       const float* __restrict__ vp, const float* __restrict__ spw,
                       const float* __restrict__ inw, const float* __restrict__ opw,
                       const float* __restrict__ postw,
                       float* __restrict__ peT, unsigned short* __restrict__ wdst) {
  unsigned id = blockIdx.x * 256u + threadIdx.x;
  if (id < 16384u) {
    int p = id >> 7, j = id & 127;
    float div = expf(-9.210340371976184f * (float)(j & ~1) * (1.0f / 128.0f));
    float ang = (float)p * div;
    peT[id] = (j & 1) ? cosf(ang) : sinf(ang);
    return;
  }
  unsigned i = id - 16384u;
  if (i >= 1769472u) return;
  float v;
  if (i < 65536u)            v = qp[i];
  else if (i < 196608u)      v = kp[i - 65536u];
  else if (i < 262144u)      v = vp[i - 196608u];
  else if (i < 327680u)      v = spw[i - 262144u];
  else if (i < 524288u)      v = inw[i - 327680u];
  else if (i < 589824u)      v = opw[i - 524288u];
  else {
    // conv weights packed in per-lane MFMA fragment order:
    // idx = ((((tap*16 + cc)*8 + wid)*2 + sub)*64 + lane)*8 + e
    // oc = wid*32 + sub*16 + (lane&15); ic = cc*32 + (lane>>4)*8 + e
    unsigned r = i - 589824u;
    unsigned e = r & 7u, l = (r >> 3) & 63u, sub = (r >> 9) & 1u,
             wd = (r >> 10) & 7u, cc = (r >> 13) & 15u, tap = r >> 17;
    unsigned oc = wd * 32u + sub * 16u + (l & 15u);
    unsigned ic = cc * 32u + (l >> 4) * 8u + e;
    v = postw[(oc * 512u + ic) * 9u + tap];
  }
  wdst[i] = f2b(v);
}

// ================= shared GEMM: OUT[e][tok] += W[e][c] * X[tok][c] =================
__device__ __forceinline__ void gemm4x4(f32x4 acc[4][4], const unsigned short* __restrict__ wA,
                                        int Kw, int kw0, const unsigned short* sB, int strideB,
                                        int nK, int wid, int lane) {
  const int rA = lane & 15;
  const int kq = (lane >> 4) << 3;
  for (int ks = 0; ks < nK; ks += 32) {
    bf16x8 a[4];
#pragma unroll
    for (int rt = 0; rt < 4; ++rt)
      a[rt] = *reinterpret_cast<const bf16x8*>(wA + (wid * 64 + rt * 16 + rA) * Kw + kw0 + ks + kq);
#pragma unroll
    for (int ct = 0; ct < 4; ++ct) {
      bf16x8 bb = rd8(sB, ct * 16 + rA, strideB, ks + kq);
#pragma unroll
      for (int rt = 0; rt < 4; ++rt) acc[rt][ct] = MFMA16(a[rt], bb, acc[rt][ct]);
    }
  }
}

// stage 64 tokens x 128 channels of an NCHW fp32 input into swizzled bf16 LDS
__device__ __forceinline__ void stage128(unsigned short* sB, const float* __restrict__ src,
                                         int b, int Cin, int c0, int h0, int w0, int tid) {
#pragma unroll
  for (int it = 0; it < 4; ++it) {
    int p = tid + (it << 8);
    int c = p >> 3, r = p & 7;
    const float* g = src + ((long)(b * Cin + c0 + c) * 128 + (h0 + r)) * 128 + w0;
    float4 f0 = *reinterpret_cast<const float4*>(g);
    float4 f1 = *reinterpret_cast<const float4*>(g + 4);
    float v[8] = {f0.x, f0.y, f0.z, f0.w, f1.x, f1.y, f1.z, f1.w};
#pragma unroll
    for (int i = 0; i < 8; ++i) {
      int tok = (r << 3) + i;
      sB[tok * 128 + (c ^ ((tok & 7) << 3))] = f2b(v[i]);
    }
  }
}

__device__ __forceinline__ void epi_pe_lds(unsigned short* buf, const f32x4 acc[4][4],
                                           const float* peL, int wid, int lane) {
#pragma unroll
  for (int rt = 0; rt < 4; ++rt) {
    int e0 = wid * 64 + rt * 16 + ((lane >> 4) << 2);
#pragma unroll
    for (int ct = 0; ct < 4; ++ct) {
      int tok = ct * 16 + (lane & 15);
      int r = tok >> 3, cpx = tok & 7;
      const float* pe = (e0 < 128) ? (peL + r * 128 + e0) : (peL + (8 + cpx) * 128 + (e0 - 128));
      ushort4 pk;
      pk.x = f2b(acc[rt][ct][0] + pe[0]);
      pk.y = f2b(acc[rt][ct][1] + pe[1]);
      pk.z = f2b(acc[rt][ct][2] + pe[2]);
      pk.w = f2b(acc[rt][ct][3] + pe[3]);
      *reinterpret_cast<ushort4*>(buf + tok * 256 + (e0 ^ ((tok & 7) << 3))) = pk;
    }
  }
}

__device__ __forceinline__ void epi_bias_lds(unsigned short* buf, const f32x4 acc[4][4],
                                             const float* __restrict__ bias, int wid, int lane) {
#pragma unroll
  for (int rt = 0; rt < 4; ++rt) {
    int e0 = wid * 64 + rt * 16 + ((lane >> 4) << 2);
    float4 bs = *reinterpret_cast<const float4*>(bias + e0);
#pragma unroll
    for (int ct = 0; ct < 4; ++ct) {
      int tok = ct * 16 + (lane & 15);
      ushort4 pk;
      pk.x = f2b(acc[rt][ct][0] + bs.x);
      pk.y = f2b(acc[rt][ct][1] + bs.y);
      pk.z = f2b(acc[rt][ct][2] + bs.z);
      pk.w = f2b(acc[rt][ct][3] + bs.w);
      *reinterpret_cast<ushort4*>(buf + tok * 256 + (e0 ^ ((tok & 7) << 3))) = pk;
    }
  }
}

// y_t layout: [b][cc=ch/32][h][w][ch%32]
__device__ __forceinline__ void epi_global(unsigned short* __restrict__ y_t, const f32x4 acc[4][4],
                                           const float* __restrict__ bias, int chOff,
                                           int b, int h0, int w0, int wid, int lane) {
#pragma unroll
  for (int rt = 0; rt < 4; ++rt) {
    int e0 = wid * 64 + rt * 16 + ((lane >> 4) << 2);
    float4 bs = bias ? *reinterpret_cast<const float4*>(bias + e0) : make_float4(0.f, 0.f, 0.f, 0.f);
    int ch = chOff + e0;
#pragma unroll
    for (int ct = 0; ct < 4; ++ct) {
      int tok = ct * 16 + (lane & 15);
      int r = tok >> 3, cpx = tok & 7;
      long gy = ((((long)(b * 16 + (ch >> 5)) * 128 + (h0 + r)) * 128 + (w0 + cpx)) << 5) + (ch & 31);
      ushort4 pk;
      pk.x = f2b(acc[rt][ct][0] + bs.x);
      pk.y = f2b(acc[rt][ct][1] + bs.y);
      pk.z = f2b(acc[rt][ct][2] + bs.z);
      pk.w = f2b(acc[rt][ct][3] + bs.w);
      *reinterpret_cast<ushort4*>(y_t + gy) = pk;
    }
  }
}

// ================= fused: projections + PE + window MHA + out-proj + skip =================
__launch_bounds__(256, 1)
__global__ void k_attn(const float* __restrict__ x5, const float* __restrict__ d1,
                       const float* __restrict__ d2,
                       const unsigned short* __restrict__ w_qp, const unsigned short* __restrict__ w_kp,
                       const unsigned short* __restrict__ w_vp, const unsigned short* __restrict__ w_sp,
                       const unsigned short* __restrict__ w_in, const unsigned short* __restrict__ w_op,
                       const float* __restrict__ in_b, const float* __restrict__ out_b,
                       const float* __restrict__ peT, unsigned short* __restrict__ y_t) {
  extern __shared__ unsigned short sm[];
  unsigned short* bufQ = sm;              // [64][256]  q -> qh
  unsigned short* bufK = sm + 16384;      // [64][256]  k -> kh
  unsigned short* bufV = sm + 32768;      // [64][256]  v -> o
  unsigned short* bufX = sm + 49152;      // peL (float[16][128]) then vhT [256][64]
  unsigned short* bufI = sm + 65536;      // [64][128] staging; later P [64][64]
  float* peL = reinterpret_cast<float*>(bufX);

  const int tid = threadIdx.x;
  const int lane = tid & 63;
  const int wid = tid >> 6;
  const int kq = (lane >> 4) << 3;
  const int win = blockIdx.x;
  const int b = win >> 8, wh = (win >> 4) & 15, ww = win & 15;
  const int h0 = wh * 8, w0 = ww * 8;

  for (int i = tid; i < 2048; i += 256) {
    int rr = i >> 7, e = i & 127;
    int p = (rr < 8) ? (h0 + rr) : (w0 + rr - 8);
    peL[i] = peT[p * 128 + e];
  }

  const f32x4 vz = {0.f, 0.f, 0.f, 0.f};
  f32x4 accA[4][4], accB[4][4];

  // ---- q & skip (from d1) ----
#pragma unroll
  for (int i = 0; i < 4; ++i)
#pragma unroll
    for (int j = 0; j < 4; ++j) { accA[i][j] = vz; accB[i][j] = vz; }
  for (int c0 = 0; c0 < 256; c0 += 128) {
    __syncthreads();
    stage128(bufI, d1, b, 256, c0, h0, w0, tid);
    __syncthreads();
    gemm4x4(accA, w_qp, 256, c0, bufI, 128, 128, wid, lane);
    gemm4x4(accB, w_sp, 256, c0, bufI, 128, 128, wid, lane);
  }
  epi_pe_lds(bufQ, accA, peL, wid, lane);
  epi_global(y_t, accB, nullptr, 256, b, h0, w0, wid, lane);   // skip -> channels 256..511

  // ---- k (from x5, K=512) ----
#pragma unroll
  for (int i = 0; i < 4; ++i)
#pragma unroll
    for (int j = 0; j < 4; ++j) accA[i][j] = vz;
  for (int c0 = 0; c0 < 512; c0 += 128) {
    __syncthreads();
    stage128(bufI, x5, b, 512, c0, h0, w0, tid);
    __syncthreads();
    gemm4x4(accA, w_kp, 512, c0, bufI, 128, 128, wid, lane);
  }
  epi_pe_lds(bufK, accA, peL, wid, lane);

  // ---- v (from d2) ----
#pragma unroll
  for (int i = 0; i < 4; ++i)
#pragma unroll
    for (int j = 0; j < 4; ++j) accA[i][j] = vz;
  for (int c0 = 0; c0 < 256; c0 += 128) {
    __syncthreads();
    stage128(bufI, d2, b, 256, c0, h0, w0, tid);
    __syncthreads();
    gemm4x4(accA, w_vp, 256, c0, bufI, 128, 128, wid, lane);
  }
  epi_pe_lds(bufV, accA, peL, wid, lane);

  __syncthreads();

  // ---- qh ----
#pragma unroll
  for (int i = 0; i < 4; ++i)
#pragma unroll
    for (int j = 0; j < 4; ++j) accA[i][j] = vz;
  gemm4x4(accA, w_in, 256, 0, bufQ, 256, 256, wid, lane);
  __syncthreads();
  epi_bias_lds(bufQ, accA, in_b, wid, lane);

  // ---- kh ----
#pragma unroll
  for (int i = 0; i < 4; ++i)
#pragma unroll
    for (int j = 0; j < 4; ++j) accA[i][j] = vz;
  gemm4x4(accA, w_in + 65536, 256, 0, bufK, 256, 256, wid, lane);
  __syncthreads();
  epi_bias_lds(bufK, accA, in_b + 256, wid, lane);

  // ---- vh -> transposed vhT [ch][tok] in bufX ----
#pragma unroll
  for (int i = 0; i < 4; ++i)
#pragma unroll
    for (int j = 0; j < 4; ++j) accA[i][j] = vz;
  gemm4x4(accA, w_in + 131072, 256, 0, bufV, 256, 256, wid, lane);
  __syncthreads();
  {
    unsigned short* vhT = bufX;
#pragma unroll
    for (int rt = 0; rt < 4; ++rt) {
      int e0 = wid * 64 + rt * 16 + ((lane >> 4) << 2);
      float4 bs = *reinterpret_cast<const float4*>(in_b + 512 + e0);
      float bsv[4] = {bs.x, bs.y, bs.z, bs.w};
#pragma unroll
      for (int ct = 0; ct < 4; ++ct) {
        int tok = ct * 16 + (lane & 15);
#pragma unroll
        for (int j = 0; j < 4; ++j) {
          int ch = e0 + j;
          vhT[ch * 64 + (tok ^ ((ch & 7) << 3))] = f2b(accA[rt][ct][j] + bsv[j]);
        }
      }
    }
  }
  __syncthreads();

  // ---- per-head attention; o accumulates into bufV ----
  unsigned short* Pb = bufI;
  unsigned short* vhT = bufX;
  const float scl = 0.17677669529663687f;
  for (int hd = 0; hd < 8; ++hd) {
    f32x4 sv[4];
#pragma unroll
    for (int ct = 0; ct < 4; ++ct) sv[ct] = vz;
    {
      bf16x8 aq = rd8(bufQ, wid * 16 + (lane & 15), 256, hd * 32 + kq);
#pragma unroll
      for (int ct = 0; ct < 4; ++ct) {
        bf16x8 bk = rd8(bufK, ct * 16 + (lane & 15), 256, hd * 32 + kq);
        sv[ct] = MFMA16(aq, bk, sv[ct]);
      }
    }
    float pr[4][4];
#pragma unroll
    for (int j = 0; j < 4; ++j) {
      float mx = fmaxf(fmaxf(sv[0][j], sv[1][j]), fmaxf(sv[2][j], sv[3][j])) * scl;
#pragma unroll
      for (int m = 8; m >= 1; m >>= 1) mx = fmaxf(mx, __shfl_xor(mx, m));
      float sum = 0.f;
#pragma unroll
      for (int ct = 0; ct < 4; ++ct) {
        float p = __expf(sv[ct][j] * scl - mx);
        pr[ct][j] = p;
        sum += p;
      }
#pragma unroll
      for (int m = 8; m >= 1; m >>= 1) sum += __shfl_xor(sum, m);
      float inv = 1.f / sum;
#pragma unroll
      for (int ct = 0; ct < 4; ++ct) pr[ct][j] *= inv;
    }
#pragma unroll
    for (int ct = 0; ct < 4; ++ct)
#pragma unroll
      for (int j = 0; j < 4; ++j) {
        int q = wid * 16 + ((lane >> 4) << 2) + j;
        int kt = ct * 16 + (lane & 15);
        Pb[q * 64 + (kt ^ ((q & 7) << 3))] = f2b(pr[ct][j]);
      }
    f32x4 ov[2];
    ov[0] = vz; ov[1] = vz;
#pragma unroll
    for (int ks = 0; ks < 64; ks += 32) {
      bf16x8 bp = rd8(Pb, wid * 16 + (lane & 15), 64, ks + kq);
#pragma unroll
      for (int rt = 0; rt < 2; ++rt) {
        bf16x8 av = rd8(vhT, hd * 32 + rt * 16 + (lane & 15), 64, ks + kq);
        ov[rt] = MFMA16(av, bp, ov[rt]);
      }
    }
#pragma unroll
    for (int rt = 0; rt < 2; ++rt) {
      int ch0 = hd * 32 + rt * 16 + ((lane >> 4) << 2);
      int tok = wid * 16 + (lane & 15);
      ushort4 pk;
      pk.x = f2b(ov[rt][0]);
      pk.y = f2b(ov[rt][1]);
      pk.z = f2b(ov[rt][2]);
      pk.w = f2b(ov[rt][3]);
      *reinterpret_cast<ushort4*>(bufV + tok * 256 + (ch0 ^ ((tok & 7) << 3))) = pk;
    }
  }
  __syncthreads();

  // ---- out projection -> y_t channels 0..255 ----
#pragma unroll
  for (int i = 0; i < 4; ++i)
#pragma unroll
    for (int j = 0; j < 4; ++j) accA[i][j] = vz;
  gemm4x4(accA, w_op, 256, 0, bufV, 256, 256, wid, lane);
  epi_global(y_t, accA, out_b, 0, b, h0, w0, wid, lane);
}

// ================= conv 3x3 (512->256) implicit GEMM =================
// y_t: [b][16cc][128h][128w][32c] bf16; weights fragment-packed; out NCHW fp32
#define PATCH_ELEMS 10368   // 324 px * 32 ch

__device__ __forceinline__ void conv_loadp(const unsigned short* __restrict__ y_t,
                                           int b, int cc, int h0, int w0, int tid, uint4* pv) {
#pragma unroll
  for (int it = 0; it < 3; ++it) {
    int i = tid + (it << 9);
    uint4 v = make_uint4(0u, 0u, 0u, 0u);
    if (i < 1296) {
      int pidx = i >> 2, g = i & 3;
      int pr = pidx / 18, pc = pidx - pr * 18;
      int hh = h0 + pr - 1, wp = w0 + pc - 1;
      if ((unsigned)hh < 128u && (unsigned)wp < 128u)
        v = *reinterpret_cast<const uint4*>(
            y_t + ((((long)(b * 16 + cc) * 128 + hh) * 128 + wp) << 5) + (g << 3));
    }
    pv[it] = v;
  }
}

__device__ __forceinline__ void conv_storep(unsigned short* buf, int tid, const uint4* pv) {
#pragma unroll
  for (int it = 0; it < 3; ++it) {
    int i = tid + (it << 9);
    if (i < 1296) {
      int pidx = i >> 2, g = i & 3;
      int off = (pidx << 5) + ((g ^ ((pidx >> 1) & 3)) << 3);
      *reinterpret_cast<uint4*>(buf + off) = pv[it];
    }
  }
}

__launch_bounds__(512, 1)
__global__ void k_conv(const unsigned short* __restrict__ y_t, const unsigned short* __restrict__ wc,
                       float* __restrict__ out) {
  __shared__ unsigned short sp_[2][PATCH_ELEMS];
  const int tid = threadIdx.x, lane = tid & 63, wid = tid >> 6;
  const int gq = lane >> 4;
  const int bi = blockIdx.x;
  const int b = bi >> 6, t = bi & 63, ty = t >> 3, tx = t & 7;
  const int h0 = ty * 16, w0 = tx * 16;

  const f32x4 vz = {0.f, 0.f, 0.f, 0.f};
  f32x4 acc[2][16];
#pragma unroll
  for (int rt = 0; rt < 2; ++rt)
#pragma unroll
    for (int ct = 0; ct < 16; ++ct) acc[rt][ct] = vz;

  uint4 pv[3];
  conv_loadp(y_t, b, 0, h0, w0, tid, pv);
  conv_storep(sp_[0], tid, pv);
  __syncthreads();

#pragma unroll 1
  for (int cc = 0; cc < 16; ++cc) {
    const unsigned short* buf = sp_[cc & 1];
    if (cc < 15) conv_loadp(y_t, b, cc + 1, h0, w0, tid, pv);   // issue early (T14)

#pragma unroll
    for (int ky = 0; ky < 3; ++ky)
#pragma unroll
      for (int kx = 0; kx < 3; ++kx) {
        const int tap = ky * 3 + kx;
        // coalesced fragment loads: lane*16B, full cacheline use
        const unsigned short* wt = wc + (((((tap << 4) + cc) << 3) + wid) << 10) + (lane << 3);
        bf16x8 a0 = *reinterpret_cast<const bf16x8*>(wt);
        bf16x8 a1 = *reinterpret_cast<const bf16x8*>(wt + 512);
#pragma unroll
        for (int ct = 0; ct < 16; ++ct) {
          int prow = (ct + ky) * 18 + (lane & 15) + kx;
          int boff = (prow << 5) + ((gq ^ ((prow >> 1) & 3)) << 3);
          bf16x8 bb = *reinterpret_cast<const bf16x8*>(buf + boff);
          acc[0][ct] = MFMA16(a0, bb, acc[0][ct]);
          acc[1][ct] = MFMA16(a1, bb, acc[1][ct]);
        }
      }

    if (cc < 15) conv_storep(sp_[(cc + 1) & 1], tid, pv);       // write late
    __syncthreads();
  }

  // epilogue: rows = oc, cols = px
#pragma unroll
  for (int rt = 0; rt < 2; ++rt) {
    int oc0 = wid * 32 + rt * 16 + ((lane >> 4) << 2);
#pragma unroll
    for (int ct = 0; ct < 16; ++ct) {
      int hh = h0 + ct, wp = w0 + (lane & 15);
      long base = (((long)(b * 256 + oc0)) * 128 + hh) * 128 + wp;
#pragma unroll
      for (int j = 0; j < 4; ++j) out[base + (long)j * 16384] = acc[rt][ct][j];
    }
  }
}

// ================= BN stats / finalize / apply =================
__global__ void k_stats(const float* __restrict__ out, float* __restrict__ sums) {
  __shared__ float s1[256], s2[256];
  int c = blockIdx.x, tid = threadIdx.x;
  float a1 = 0.f, a2 = 0.f;
  for (int bb = 0; bb < 8; ++bb) {
    const float* p = out + ((long)(bb * 256 + c)) * 16384;
    for (int i = tid; i < 16384; i += 256) { float v = p[i]; a1 += v; a2 += v * v; }
  }
  s1[tid] = a1; s2[tid] = a2;
  __syncthreads();
  for (int s = 128; s > 0; s >>= 1) {
    if (tid < s) { s1[tid] += s1[tid + s]; s2[tid] += s2[tid + s]; }
    __syncthreads();
  }
  if (tid == 0) { sums[c] = s1[0]; sums[256 + c] = s2[0]; }
}

__global__ void k_final(const float* __restrict__ sums, const float* __restrict__ gamma,
                        const float* __restrict__ beta, float* __restrict__ sc) {
  int c = threadIdx.x;
  float mean = sums[c] * (1.f / 131072.f);
  float var = sums[256 + c] * (1.f / 131072.f) - mean * mean;
  float s = gamma[c] * rsqrtf(var + 1e-5f);
  sc[c] = s;
  sc[256 + c] = beta[c] - mean * s;
}

__global__ void k_apply(float* __restrict__ out, const float* __restrict__ sc) {
  const long n4 = 33554432 / 4;
  for (long i4 = (long)blockIdx.x * 256 + threadIdx.x; i4 < n4; i4 += (long)gridDim.x * 256) {
    float4 v = reinterpret_cast<float4*>(out)[i4];
    int c = (int)((i4 >> 12) & 255);
    float s = sc[c], sh = sc[256 + c];
    v.x = fmaxf(v.x * s + sh, 0.f);
    v.y = fmaxf(v.y * s + sh, 0.f);
    v.z = fmaxf(v.z * s + sh, 0.f);
    v.w = fmaxf(v.w * s + sh, 0.f);
    reinterpret_cast<float4*>(out)[i4] = v;
  }
}

// ================= launch =================
extern "C" void kernel_launch(void* const* d_in, const int* in_sizes, int n_in,
                              void* d_out, int out_size, void* d_ws, size_t ws_size,
                              hipStream_t stream) {
  const float* x5 = (const float*)d_in[0];
  const float* d1 = (const float*)d_in[1];
  const float* d2 = (const float*)d_in[2];
  const float* kp = (const float*)d_in[3];
  const float* qp = (const float*)d_in[4];
  const float* vp = (const float*)d_in[5];
  const float* spw = (const float*)d_in[6];
  const float* inw = (const float*)d_in[7];
  const float* inb = (const float*)d_in[8];
  const float* opw = (const float*)d_in[9];
  const float* opb = (const float*)d_in[10];
  const float* pw = (const float*)d_in[11];
  const float* gamma = (const float*)d_in[12];
  const float* beta = (const float*)d_in[13];

  if (ws_size < (size_t)WSO_TOTAL) {
    fprintf(stderr, "kernel_launch: ws too small: %zu < %u\n", ws_size, WSO_TOTAL);
    return;
  }

  char* ws = (char*)d_ws;
  float* peT = (float*)(ws + WSO_PE);
  unsigned short* w_qp = (unsigned short*)(ws + WSO_WQP);
  unsigned short* w_kp = (unsigned short*)(ws + WSO_WKP);
  unsigned short* w_vp = (unsigned short*)(ws + WSO_WVP);
  unsigned short* w_sp = (unsigned short*)(ws + WSO_WSP);
  unsigned short* w_in = (unsigned short*)(ws + WSO_WIN);
  unsigned short* w_op = (unsigned short*)(ws + WSO_WOP);
  unsigned short* w_c = (unsigned short*)(ws + WSO_WC);
  unsigned short* y_t = (unsigned short*)(ws + WSO_YT);
  float* sums = (float*)(ws + WSO_SUMS);
  float* sc = (float*)(ws + WSO_SC);

  hipFuncSetAttribute(reinterpret_cast<const void*>(k_attn),
                      hipFuncAttributeMaxDynamicSharedMemorySize, SMEM_ATTN);

  k_prep<<<6976, 256, 0, stream>>>(qp, kp, vp, spw, inw, opw, pw, peT, w_qp);
  k_attn<<<2048, 256, SMEM_ATTN, stream>>>(x5, d1, d2, w_qp, w_kp, w_vp, w_sp, w_in, w_op,
                                           inb, opb, peT, y_t);
  k_conv<<<512, 512, 0, stream>>>(y_t, w_c, (float*)d_out);
  k_stats<<<256, 256, 0, stream>>>((const float*)d_out, sums);
  k_final<<<1, 256, 0, stream>>>(sums, gamma, beta, sc);
  k_apply<<<2048, 256, 0, stream>>>((float*)d_out, sc);
}

// Round 3
// 1847.649 us; speedup vs baseline: 1.8125x; 1.3554x over previous
//
#include <hip/hip_runtime.h>
#include <cstdio>
#include <cmath>

typedef __attribute__((ext_vector_type(8))) short bf16x8;
typedef __attribute__((ext_vector_type(4))) float f32x4;

#define MFMA16(a, b, c) __builtin_amdgcn_mfma_f32_16x16x32_bf16((a), (b), (c), 0, 0, 0)

// ---------------- workspace layout (byte offsets) ----------------
#define WSO_PE    0u                          // float[128*128]
#define WSO_WQP   65536u                      // bf16 [256][256]
#define WSO_WKP   (WSO_WQP + 131072u)         // bf16 [256][512]
#define WSO_WVP   (WSO_WKP + 262144u)         // bf16 [256][256]
#define WSO_WSP   (WSO_WVP + 131072u)         // bf16 [256][256]
#define WSO_WIN   (WSO_WSP + 131072u)         // bf16 [768][256] (Wq|Wk|Wv)
#define WSO_WOP   (WSO_WIN + 393216u)         // bf16 [256][256]
#define WSO_WC    (WSO_WOP + 131072u)         // bf16 [9][16][8][2][512] fragment-packed
#define WSO_YT    (WSO_WC + 2359296u)         // bf16 [8][16cc][128][128][32c]  (conv input)
#define WSO_SUMS  (WSO_YT + 134217728u)       // float[512] (sum | sumsq)
#define WSO_SC    (WSO_SUMS + 2048u)          // float[512] (scale | shift)
#define WSO_TOTAL (WSO_SC + 2048u)

#define SMEM_ATTN 147456

__device__ __forceinline__ unsigned short f2b(float x) {
  unsigned int u = __builtin_bit_cast(unsigned int, x);
  u += 0x7fffu + ((u >> 16) & 1u);
  return (unsigned short)(u >> 16);
}

// swizzled LDS 8-element bf16 read; same swizzle used by every LDS writer (256/128-stride bufs)
__device__ __forceinline__ bf16x8 rd8(const unsigned short* s, int row, int stride, int k) {
  return *reinterpret_cast<const bf16x8*>(s + row * stride + (k ^ ((row & 7) << 3)));
}

// ================= prep: pe table + all weight conversions =================
__global__ void k_prep(const float* __restrict__ qp, const float* __restrict__ kp,
                       const float* __restrict__ vp, const float* __restrict__ spw,
                       const float* __restrict__ inw, const float* __restrict__ opw,
                       const float* __restrict__ postw,
                       float* __restrict__ peT, unsigned short* __restrict__ wdst) {
  unsigned id = blockIdx.x * 256u + threadIdx.x;
  if (id < 16384u) {
    int p = id >> 7, j = id & 127;
    float div = expf(-9.210340371976184f * (float)(j & ~1) * (1.0f / 128.0f));
    float ang = (float)p * div;
    peT[id] = (j & 1) ? cosf(ang) : sinf(ang);
    return;
  }
  unsigned i = id - 16384u;
  if (i >= 1769472u) return;
  float v;
  if (i < 65536u)            v = qp[i];
  else if (i < 196608u)      v = kp[i - 65536u];
  else if (i < 262144u)      v = vp[i - 196608u];
  else if (i < 327680u)      v = spw[i - 262144u];
  else if (i < 524288u)      v = inw[i - 327680u];
  else if (i < 589824u)      v = opw[i - 524288u];
  else {
    // conv weights packed in per-lane MFMA fragment order:
    // idx = ((((tap*16 + cc)*8 + wo)*2 + rt)*64 + lane)*8 + e
    // oc = wo*32 + rt*16 + (lane&15); ic = cc*32 + (lane>>4)*8 + e
    unsigned r = i - 589824u;
    unsigned e = r & 7u, l = (r >> 3) & 63u, sub = (r >> 9) & 1u,
             wd = (r >> 10) & 7u, cc = (r >> 13) & 15u, tap = r >> 17;
    unsigned oc = wd * 32u + sub * 16u + (l & 15u);
    unsigned ic = cc * 32u + (l >> 4) * 8u + e;
    v = postw[(oc * 512u + ic) * 9u + tap];
  }
  wdst[i] = f2b(v);
}

// ================= shared GEMM: OUT[e][tok] += W[e][c] * X[tok][c] =================
__device__ __forceinline__ void gemm4x4(f32x4 acc[4][4], const unsigned short* __restrict__ wA,
                                        int Kw, int kw0, const unsigned short* sB, int strideB,
                                        int nK, int wid, int lane) {
  const int rA = lane & 15;
  const int kq = (lane >> 4) << 3;
  for (int ks = 0; ks < nK; ks += 32) {
    bf16x8 a[4];
#pragma unroll
    for (int rt = 0; rt < 4; ++rt)
      a[rt] = *reinterpret_cast<const bf16x8*>(wA + (wid * 64 + rt * 16 + rA) * Kw + kw0 + ks + kq);
#pragma unroll
    for (int ct = 0; ct < 4; ++ct) {
      bf16x8 bb = rd8(sB, ct * 16 + rA, strideB, ks + kq);
#pragma unroll
      for (int rt = 0; rt < 4; ++rt) acc[rt][ct] = MFMA16(a[rt], bb, acc[rt][ct]);
    }
  }
}

// stage 64 tokens x 128 channels of an NCHW fp32 input into swizzled bf16 LDS
__device__ __forceinline__ void stage128(unsigned short* sB, const float* __restrict__ src,
                                         int b, int Cin, int c0, int h0, int w0, int tid) {
#pragma unroll
  for (int it = 0; it < 4; ++it) {
    int p = tid + (it << 8);
    int c = p >> 3, r = p & 7;
    const float* g = src + ((long)(b * Cin + c0 + c) * 128 + (h0 + r)) * 128 + w0;
    float4 f0 = *reinterpret_cast<const float4*>(g);
    float4 f1 = *reinterpret_cast<const float4*>(g + 4);
    float v[8] = {f0.x, f0.y, f0.z, f0.w, f1.x, f1.y, f1.z, f1.w};
#pragma unroll
    for (int i = 0; i < 8; ++i) {
      int tok = (r << 3) + i;
      sB[tok * 128 + (c ^ ((tok & 7) << 3))] = f2b(v[i]);
    }
  }
}

__device__ __forceinline__ void epi_pe_lds(unsigned short* buf, const f32x4 acc[4][4],
                                           const float* peL, int wid, int lane) {
#pragma unroll
  for (int rt = 0; rt < 4; ++rt) {
    int e0 = wid * 64 + rt * 16 + ((lane >> 4) << 2);
#pragma unroll
    for (int ct = 0; ct < 4; ++ct) {
      int tok = ct * 16 + (lane & 15);
      int r = tok >> 3, cpx = tok & 7;
      const float* pe = (e0 < 128) ? (peL + r * 128 + e0) : (peL + (8 + cpx) * 128 + (e0 - 128));
      ushort4 pk;
      pk.x = f2b(acc[rt][ct][0] + pe[0]);
      pk.y = f2b(acc[rt][ct][1] + pe[1]);
      pk.z = f2b(acc[rt][ct][2] + pe[2]);
      pk.w = f2b(acc[rt][ct][3] + pe[3]);
      *reinterpret_cast<ushort4*>(buf + tok * 256 + (e0 ^ ((tok & 7) << 3))) = pk;
    }
  }
}

__device__ __forceinline__ void epi_bias_lds(unsigned short* buf, const f32x4 acc[4][4],
                                             const float* __restrict__ bias, int wid, int lane) {
#pragma unroll
  for (int rt = 0; rt < 4; ++rt) {
    int e0 = wid * 64 + rt * 16 + ((lane >> 4) << 2);
    float4 bs = *reinterpret_cast<const float4*>(bias + e0);
#pragma unroll
    for (int ct = 0; ct < 4; ++ct) {
      int tok = ct * 16 + (lane & 15);
      ushort4 pk;
      pk.x = f2b(acc[rt][ct][0] + bs.x);
      pk.y = f2b(acc[rt][ct][1] + bs.y);
      pk.z = f2b(acc[rt][ct][2] + bs.z);
      pk.w = f2b(acc[rt][ct][3] + bs.w);
      *reinterpret_cast<ushort4*>(buf + tok * 256 + (e0 ^ ((tok & 7) << 3))) = pk;
    }
  }
}

// y_t layout: [b][cc=ch/32][h][w][ch%32]
__device__ __forceinline__ void epi_global(unsigned short* __restrict__ y_t, const f32x4 acc[4][4],
                                           const float* __restrict__ bias, int chOff,
                                           int b, int h0, int w0, int wid, int lane) {
#pragma unroll
  for (int rt = 0; rt < 4; ++rt) {
    int e0 = wid * 64 + rt * 16 + ((lane >> 4) << 2);
    float4 bs = bias ? *reinterpret_cast<const float4*>(bias + e0) : make_float4(0.f, 0.f, 0.f, 0.f);
    int ch = chOff + e0;
#pragma unroll
    for (int ct = 0; ct < 4; ++ct) {
      int tok = ct * 16 + (lane & 15);
      int r = tok >> 3, cpx = tok & 7;
      long gy = ((((long)(b * 16 + (ch >> 5)) * 128 + (h0 + r)) * 128 + (w0 + cpx)) << 5) + (ch & 31);
      ushort4 pk;
      pk.x = f2b(acc[rt][ct][0] + bs.x);
      pk.y = f2b(acc[rt][ct][1] + bs.y);
      pk.z = f2b(acc[rt][ct][2] + bs.z);
      pk.w = f2b(acc[rt][ct][3] + bs.w);
      *reinterpret_cast<ushort4*>(y_t + gy) = pk;
    }
  }
}

// ================= fused: projections + PE + window MHA + out-proj + skip =================
__launch_bounds__(256, 1)
__global__ void k_attn(const float* __restrict__ x5, const float* __restrict__ d1,
                       const float* __restrict__ d2,
                       const unsigned short* __restrict__ w_qp, const unsigned short* __restrict__ w_kp,
                       const unsigned short* __restrict__ w_vp, const unsigned short* __restrict__ w_sp,
                       const unsigned short* __restrict__ w_in, const unsigned short* __restrict__ w_op,
                       const float* __restrict__ in_b, const float* __restrict__ out_b,
                       const float* __restrict__ peT, unsigned short* __restrict__ y_t) {
  extern __shared__ unsigned short sm[];
  unsigned short* bufQ = sm;              // [64][256]  q -> qh
  unsigned short* bufK = sm + 16384;      // [64][256]  k -> kh
  unsigned short* bufV = sm + 32768;      // [64][256]  v -> o
  unsigned short* bufX = sm + 49152;      // peL (float[16][128]) then vhT [256][64]
  unsigned short* bufI = sm + 65536;      // [64][128] staging; later P [64][64]
  float* peL = reinterpret_cast<float*>(bufX);

  const int tid = threadIdx.x;
  const int lane = tid & 63;
  const int wid = tid >> 6;
  const int kq = (lane >> 4) << 3;
  const int win = blockIdx.x;
  const int b = win >> 8, wh = (win >> 4) & 15, ww = win & 15;
  const int h0 = wh * 8, w0 = ww * 8;

  for (int i = tid; i < 2048; i += 256) {
    int rr = i >> 7, e = i & 127;
    int p = (rr < 8) ? (h0 + rr) : (w0 + rr - 8);
    peL[i] = peT[p * 128 + e];
  }

  const f32x4 vz = {0.f, 0.f, 0.f, 0.f};
  f32x4 accA[4][4], accB[4][4];

  // ---- q & skip (from d1) ----
#pragma unroll
  for (int i = 0; i < 4; ++i)
#pragma unroll
    for (int j = 0; j < 4; ++j) { accA[i][j] = vz; accB[i][j] = vz; }
  for (int c0 = 0; c0 < 256; c0 += 128) {
    __syncthreads();
    stage128(bufI, d1, b, 256, c0, h0, w0, tid);
    __syncthreads();
    gemm4x4(accA, w_qp, 256, c0, bufI, 128, 128, wid, lane);
    gemm4x4(accB, w_sp, 256, c0, bufI, 128, 128, wid, lane);
  }
  epi_pe_lds(bufQ, accA, peL, wid, lane);
  epi_global(y_t, accB, nullptr, 256, b, h0, w0, wid, lane);   // skip -> channels 256..511

  // ---- k (from x5, K=512) ----
#pragma unroll
  for (int i = 0; i < 4; ++i)
#pragma unroll
    for (int j = 0; j < 4; ++j) accA[i][j] = vz;
  for (int c0 = 0; c0 < 512; c0 += 128) {
    __syncthreads();
    stage128(bufI, x5, b, 512, c0, h0, w0, tid);
    __syncthreads();
    gemm4x4(accA, w_kp, 512, c0, bufI, 128, 128, wid, lane);
  }
  epi_pe_lds(bufK, accA, peL, wid, lane);

  // ---- v (from d2) ----
#pragma unroll
  for (int i = 0; i < 4; ++i)
#pragma unroll
    for (int j = 0; j < 4; ++j) accA[i][j] = vz;
  for (int c0 = 0; c0 < 256; c0 += 128) {
    __syncthreads();
    stage128(bufI, d2, b, 256, c0, h0, w0, tid);
    __syncthreads();
    gemm4x4(accA, w_vp, 256, c0, bufI, 128, 128, wid, lane);
  }
  epi_pe_lds(bufV, accA, peL, wid, lane);

  __syncthreads();

  // ---- qh ----
#pragma unroll
  for (int i = 0; i < 4; ++i)
#pragma unroll
    for (int j = 0; j < 4; ++j) accA[i][j] = vz;
  gemm4x4(accA, w_in, 256, 0, bufQ, 256, 256, wid, lane);
  __syncthreads();
  epi_bias_lds(bufQ, accA, in_b, wid, lane);

  // ---- kh ----
#pragma unroll
  for (int i = 0; i < 4; ++i)
#pragma unroll
    for (int j = 0; j < 4; ++j) accA[i][j] = vz;
  gemm4x4(accA, w_in + 65536, 256, 0, bufK, 256, 256, wid, lane);
  __syncthreads();
  epi_bias_lds(bufK, accA, in_b + 256, wid, lane);

  // ---- vh -> transposed vhT [ch][tok] in bufX ----
#pragma unroll
  for (int i = 0; i < 4; ++i)
#pragma unroll
    for (int j = 0; j < 4; ++j) accA[i][j] = vz;
  gemm4x4(accA, w_in + 131072, 256, 0, bufV, 256, 256, wid, lane);
  __syncthreads();
  {
    unsigned short* vhT = bufX;
#pragma unroll
    for (int rt = 0; rt < 4; ++rt) {
      int e0 = wid * 64 + rt * 16 + ((lane >> 4) << 2);
      float4 bs = *reinterpret_cast<const float4*>(in_b + 512 + e0);
      float bsv[4] = {bs.x, bs.y, bs.z, bs.w};
#pragma unroll
      for (int ct = 0; ct < 4; ++ct) {
        int tok = ct * 16 + (lane & 15);
#pragma unroll
        for (int j = 0; j < 4; ++j) {
          int ch = e0 + j;
          vhT[ch * 64 + (tok ^ ((ch & 7) << 3))] = f2b(accA[rt][ct][j] + bsv[j]);
        }
      }
    }
  }
  __syncthreads();

  // ---- per-head attention; o accumulates into bufV ----
  unsigned short* Pb = bufI;
  unsigned short* vhT = bufX;
  const float scl = 0.17677669529663687f;
  for (int hd = 0; hd < 8; ++hd) {
    f32x4 sv[4];
#pragma unroll
    for (int ct = 0; ct < 4; ++ct) sv[ct] = vz;
    {
      bf16x8 aq = rd8(bufQ, wid * 16 + (lane & 15), 256, hd * 32 + kq);
#pragma unroll
      for (int ct = 0; ct < 4; ++ct) {
        bf16x8 bk = rd8(bufK, ct * 16 + (lane & 15), 256, hd * 32 + kq);
        sv[ct] = MFMA16(aq, bk, sv[ct]);
      }
    }
    float pr[4][4];
#pragma unroll
    for (int j = 0; j < 4; ++j) {
      float mx = fmaxf(fmaxf(sv[0][j], sv[1][j]), fmaxf(sv[2][j], sv[3][j])) * scl;
#pragma unroll
      for (int m = 8; m >= 1; m >>= 1) mx = fmaxf(mx, __shfl_xor(mx, m));
      float sum = 0.f;
#pragma unroll
      for (int ct = 0; ct < 4; ++ct) {
        float p = __expf(sv[ct][j] * scl - mx);
        pr[ct][j] = p;
        sum += p;
      }
#pragma unroll
      for (int m = 8; m >= 1; m >>= 1) sum += __shfl_xor(sum, m);
      float inv = 1.f / sum;
#pragma unroll
      for (int ct = 0; ct < 4; ++ct) pr[ct][j] *= inv;
    }
#pragma unroll
    for (int ct = 0; ct < 4; ++ct)
#pragma unroll
      for (int j = 0; j < 4; ++j) {
        int q = wid * 16 + ((lane >> 4) << 2) + j;
        int kt = ct * 16 + (lane & 15);
        Pb[q * 64 + (kt ^ ((q & 7) << 3))] = f2b(pr[ct][j]);
      }
    f32x4 ov[2];
    ov[0] = vz; ov[1] = vz;
#pragma unroll
    for (int ks = 0; ks < 64; ks += 32) {
      bf16x8 bp = rd8(Pb, wid * 16 + (lane & 15), 64, ks + kq);
#pragma unroll
      for (int rt = 0; rt < 2; ++rt) {
        bf16x8 av = rd8(vhT, hd * 32 + rt * 16 + (lane & 15), 64, ks + kq);
        ov[rt] = MFMA16(av, bp, ov[rt]);
      }
    }
#pragma unroll
    for (int rt = 0; rt < 2; ++rt) {
      int ch0 = hd * 32 + rt * 16 + ((lane >> 4) << 2);
      int tok = wid * 16 + (lane & 15);
      ushort4 pk;
      pk.x = f2b(ov[rt][0]);
      pk.y = f2b(ov[rt][1]);
      pk.z = f2b(ov[rt][2]);
      pk.w = f2b(ov[rt][3]);
      *reinterpret_cast<ushort4*>(bufV + tok * 256 + (ch0 ^ ((tok & 7) << 3))) = pk;
    }
  }
  __syncthreads();

  // ---- out projection -> y_t channels 0..255 ----
#pragma unroll
  for (int i = 0; i < 4; ++i)
#pragma unroll
    for (int j = 0; j < 4; ++j) accA[i][j] = vz;
  gemm4x4(accA, w_op, 256, 0, bufV, 256, 256, wid, lane);
  epi_global(y_t, accA, out_b, 0, b, h0, w0, wid, lane);
}

// ================= conv 3x3 (512->256) implicit GEMM v3 =================
// block = 1024 thr (16 waves), tile = 256 oc x (4h x 64w) px, patch [6][66][32ic]
// per-wave acc = 32 oc x 128 px = 64 VGPRs; out rows are full 256B lines
#define CPATCH 12672   // 6*66*32 shorts

__device__ __forceinline__ void conv_loadp(const unsigned short* __restrict__ y_t,
                                           int b, int cc, int h0, int w0, int tid, uint4* pv) {
  {
    int px = tid >> 2, g = tid & 3;
    int pr = (px * 993) >> 16, pc = px - pr * 66;
    int hh = h0 + pr - 1, wp = w0 + pc - 1;
    uint4 v = make_uint4(0u, 0u, 0u, 0u);
    if ((unsigned)hh < 128u && (unsigned)wp < 128u)
      v = *reinterpret_cast<const uint4*>(
          y_t + ((((long)(b * 16 + cc) * 128 + hh) * 128 + wp) << 5) + (g << 3));
    pv[0] = v;
  }
  {
    int i = tid + 1024;
    uint4 v = make_uint4(0u, 0u, 0u, 0u);
    if (i < 1584) {
      int px = i >> 2, g = i & 3;
      int pr = (px * 993) >> 16, pc = px - pr * 66;
      int hh = h0 + pr - 1, wp = w0 + pc - 1;
      if ((unsigned)hh < 128u && (unsigned)wp < 128u)
        v = *reinterpret_cast<const uint4*>(
            y_t + ((((long)(b * 16 + cc) * 128 + hh) * 128 + wp) << 5) + (g << 3));
    }
    pv[1] = v;
  }
}

__device__ __forceinline__ void conv_storep(unsigned short* buf, int tid, const uint4* pv) {
  {
    int px = tid >> 2, g = tid & 3;
    *reinterpret_cast<uint4*>(buf + (px << 5) + ((g ^ (px & 3)) << 3)) = pv[0];
  }
  if (tid < 560) {
    int i = tid + 1024;
    int px = i >> 2, g = i & 3;
    *reinterpret_cast<uint4*>(buf + (px << 5) + ((g ^ (px & 3)) << 3)) = pv[1];
  }
}

__launch_bounds__(1024, 1)
__global__ void k_conv(const unsigned short* __restrict__ y_t, const unsigned short* __restrict__ wc,
                       float* __restrict__ out) {
  __shared__ unsigned short sp_[2][CPATCH];
  const int tid = threadIdx.x, lane = tid & 63, wid = tid >> 6;
  const int wo = wid >> 1, ph = wid & 1;     // oc-group (8x32), px-half (2x128)
  const int gq = lane >> 4, l15 = lane & 15;
  const int bi = blockIdx.x;
  const int b = bi >> 6, hs = (bi >> 1) & 31, ws = bi & 1;
  const int h0 = hs * 4, w0 = ws * 64;

  const f32x4 vz = {0.f, 0.f, 0.f, 0.f};
  f32x4 acc[2][8];
#pragma unroll
  for (int rt = 0; rt < 2; ++rt)
#pragma unroll
    for (int ct = 0; ct < 8; ++ct) acc[rt][ct] = vz;

  uint4 pv[2];
  conv_loadp(y_t, b, 0, h0, w0, tid, pv);
  conv_storep(sp_[0], tid, pv);
  __syncthreads();

#pragma unroll 1
  for (int cc = 0; cc < 16; ++cc) {
    const unsigned short* buf = sp_[cc & 1];
    if (cc < 15) conv_loadp(y_t, b, cc + 1, h0, w0, tid, pv);   // issue early (T14)

#pragma unroll
    for (int ky = 0; ky < 3; ++ky)
#pragma unroll
      for (int kx = 0; kx < 3; ++kx) {
        const int tap = ky * 3 + kx;
        // fragment-packed weights: fully-coalesced 1KB/wave loads
        const unsigned short* wt = wc + (((((tap << 4) + cc) << 3) + wo) << 10) + (lane << 3);
        bf16x8 a0 = *reinterpret_cast<const bf16x8*>(wt);
        bf16x8 a1 = *reinterpret_cast<const bf16x8*>(wt + 512);
        const int prow = (ph << 1) + ky;
#pragma unroll
        for (int ct = 0; ct < 8; ++ct) {
          int pxp = (prow + (ct >> 2)) * 66 + ((ct & 3) << 4) + l15 + kx;
          bf16x8 bb = *reinterpret_cast<const bf16x8*>(buf + (pxp << 5) + ((gq ^ (pxp & 3)) << 3));
          acc[0][ct] = MFMA16(a0, bb, acc[0][ct]);
          acc[1][ct] = MFMA16(a1, bb, acc[1][ct]);
        }
      }

    if (cc < 15) conv_storep(sp_[(cc + 1) & 1], tid, pv);       // write late
    __syncthreads();
  }

  // epilogue: oc = wo*32 + rt*16 + gq*4 + j ; px: h = ph*2 + (ct>>2), w = (ct&3)*16 + l15
#pragma unroll
  for (int rt = 0; rt < 2; ++rt) {
    int oc0 = wo * 32 + rt * 16 + gq * 4;
#pragma unroll
    for (int ct = 0; ct < 8; ++ct) {
      int hh = h0 + (ph << 1) + (ct >> 2), wp = w0 + ((ct & 3) << 4) + l15;
      long base = (((long)(b * 256 + oc0)) * 128 + hh) * 128 + wp;
#pragma unroll
      for (int j = 0; j < 4; ++j) out[base + (long)j * 16384] = acc[rt][ct][j];
    }
  }
}

// ================= BN stats / finalize / apply =================
__global__ void k_stats(const float* __restrict__ out, float* __restrict__ sums) {
  __shared__ float s1[256], s2[256];
  int c = blockIdx.x, tid = threadIdx.x;
  float a1 = 0.f, a2 = 0.f;
  for (int bb = 0; bb < 8; ++bb) {
    const float* p = out + ((long)(bb * 256 + c)) * 16384;
    for (int i = tid; i < 16384; i += 256) { float v = p[i]; a1 += v; a2 += v * v; }
  }
  s1[tid] = a1; s2[tid] = a2;
  __syncthreads();
  for (int s = 128; s > 0; s >>= 1) {
    if (tid < s) { s1[tid] += s1[tid + s]; s2[tid] += s2[tid + s]; }
    __syncthreads();
  }
  if (tid == 0) { sums[c] = s1[0]; sums[256 + c] = s2[0]; }
}

__global__ void k_final(const float* __restrict__ sums, const float* __restrict__ gamma,
                        const float* __restrict__ beta, float* __restrict__ sc) {
  int c = threadIdx.x;
  float mean = sums[c] * (1.f / 131072.f);
  float var = sums[256 + c] * (1.f / 131072.f) - mean * mean;
  float s = gamma[c] * rsqrtf(var + 1e-5f);
  sc[c] = s;
  sc[256 + c] = beta[c] - mean * s;
}

__global__ void k_apply(float* __restrict__ out, const float* __restrict__ sc) {
  const long n4 = 33554432 / 4;
  for (long i4 = (long)blockIdx.x * 256 + threadIdx.x; i4 < n4; i4 += (long)gridDim.x * 256) {
    float4 v = reinterpret_cast<float4*>(out)[i4];
    int c = (int)((i4 >> 12) & 255);
    float s = sc[c], sh = sc[256 + c];
    v.x = fmaxf(v.x * s + sh, 0.f);
    v.y = fmaxf(v.y * s + sh, 0.f);
    v.z = fmaxf(v.z * s + sh, 0.f);
    v.w = fmaxf(v.w * s + sh, 0.f);
    reinterpret_cast<float4*>(out)[i4] = v;
  }
}

// ================= launch =================
extern "C" void kernel_launch(void* const* d_in, const int* in_sizes, int n_in,
                              void* d_out, int out_size, void* d_ws, size_t ws_size,
                              hipStream_t stream) {
  const float* x5 = (const float*)d_in[0];
  const float* d1 = (const float*)d_in[1];
  const float* d2 = (const float*)d_in[2];
  const float* kp = (const float*)d_in[3];
  const float* qp = (const float*)d_in[4];
  const float* vp = (const float*)d_in[5];
  const float* spw = (const float*)d_in[6];
  const float* inw = (const float*)d_in[7];
  const float* inb = (const float*)d_in[8];
  const float* opw = (const float*)d_in[9];
  const float* opb = (const float*)d_in[10];
  const float* pw = (const float*)d_in[11];
  const float* gamma = (const float*)d_in[12];
  const float* beta = (const float*)d_in[13];

  if (ws_size < (size_t)WSO_TOTAL) {
    fprintf(stderr, "kernel_launch: ws too small: %zu < %u\n", ws_size, WSO_TOTAL);
    return;
  }

  char* ws = (char*)d_ws;
  float* peT = (float*)(ws + WSO_PE);
  unsigned short* w_qp = (unsigned short*)(ws + WSO_WQP);
  unsigned short* w_kp = (unsigned short*)(ws + WSO_WKP);
  unsigned short* w_vp = (unsigned short*)(ws + WSO_WVP);
  unsigned short* w_sp = (unsigned short*)(ws + WSO_WSP);
  unsigned short* w_in = (unsigned short*)(ws + WSO_WIN);
  unsigned short* w_op = (unsigned short*)(ws + WSO_WOP);
  unsigned short* w_c = (unsigned short*)(ws + WSO_WC);
  unsigned short* y_t = (unsigned short*)(ws + WSO_YT);
  float* sums = (float*)(ws + WSO_SUMS);
  float* sc = (float*)(ws + WSO_SC);

  hipFuncSetAttribute(reinterpret_cast<const void*>(k_attn),
                      hipFuncAttributeMaxDynamicSharedMemorySize, SMEM_ATTN);

  k_prep<<<6976, 256, 0, stream>>>(qp, kp, vp, spw, inw, opw, pw, peT, w_qp);
  k_attn<<<2048, 256, SMEM_ATTN, stream>>>(x5, d1, d2, w_qp, w_kp, w_vp, w_sp, w_in, w_op,
                                           inb, opb, peT, y_t);
  k_conv<<<512, 1024, 0, stream>>>(y_t, w_c, (float*)d_out);
  k_stats<<<256, 256, 0, stream>>>((const float*)d_out, sums);
  k_final<<<1, 256, 0, stream>>>(sums, gamma, beta, sc);
  k_apply<<<2048, 256, 0, stream>>>((float*)d_out, sc);
}

// Round 4
// 1095.619 us; speedup vs baseline: 3.0566x; 1.6864x over previous
//
#include <hip/hip_runtime.h>
#include <cstdio>
#include <cmath>

typedef __attribute__((ext_vector_type(8))) short bf16x8;
typedef __attribute__((ext_vector_type(4))) float f32x4;

#define MFMA16(a, b, c) __builtin_amdgcn_mfma_f32_16x16x32_bf16((a), (b), (c), 0, 0, 0)

// ---------------- workspace layout (byte offsets) ----------------
#define WSO_PE    0u                          // float[128*128]
#define WSO_WQP   65536u                      // bf16 [256][256]
#define WSO_WKP   (WSO_WQP + 131072u)         // bf16 [256][512]
#define WSO_WVP   (WSO_WKP + 262144u)         // bf16 [256][256]
#define WSO_WSP   (WSO_WVP + 131072u)         // bf16 [256][256]
#define WSO_WIN   (WSO_WSP + 131072u)         // bf16 [768][256] (Wq|Wk|Wv)
#define WSO_WOP   (WSO_WIN + 393216u)         // bf16 [256][256]
#define WSO_WC    (WSO_WOP + 131072u)         // bf16 [16cc][4ocb][9tap][4rt][64lane][8] fragment-packed
#define WSO_YT    (WSO_WC + 2359296u)         // bf16 [8][16cc][128][128][32c]  (conv input)
#define WSO_SUMS  (WSO_YT + 134217728u)       // float[512] (sum | sumsq)
#define WSO_SC    (WSO_SUMS + 2048u)          // float[512] (scale | shift)
#define WSO_TOTAL (WSO_SC + 2048u)

#define SMEM_ATTN 147456
#define SMEM_CONV 152064   // patch dbuf 2*19584sh + A dbuf 2*18432sh

__device__ __forceinline__ unsigned short f2b(float x) {
  unsigned int u = __builtin_bit_cast(unsigned int, x);
  u += 0x7fffu + ((u >> 16) & 1u);
  return (unsigned short)(u >> 16);
}

// swizzled LDS 8-element bf16 read; same swizzle used by every LDS writer (256/128-stride bufs)
__device__ __forceinline__ bf16x8 rd8(const unsigned short* s, int row, int stride, int k) {
  return *reinterpret_cast<const bf16x8*>(s + row * stride + (k ^ ((row & 7) << 3)));
}

// ================= prep: pe table + all weight conversions =================
__global__ void k_prep(const float* __restrict__ qp, const float* __restrict__ kp,
                       const float* __restrict__ vp, const float* __restrict__ spw,
                       const float* __restrict__ inw, const float* __restrict__ opw,
                       const float* __restrict__ postw,
                       float* __restrict__ peT, unsigned short* __restrict__ wdst) {
  unsigned id = blockIdx.x * 256u + threadIdx.x;
  if (id < 16384u) {
    int p = id >> 7, j = id & 127;
    float div = expf(-9.210340371976184f * (float)(j & ~1) * (1.0f / 128.0f));
    float ang = (float)p * div;
    peT[id] = (j & 1) ? cosf(ang) : sinf(ang);
    return;
  }
  unsigned i = id - 16384u;
  if (i >= 1769472u) return;
  float v;
  if (i < 65536u)            v = qp[i];
  else if (i < 196608u)      v = kp[i - 65536u];
  else if (i < 262144u)      v = vp[i - 196608u];
  else if (i < 327680u)      v = spw[i - 262144u];
  else if (i < 524288u)      v = inw[i - 327680u];
  else if (i < 589824u)      v = opw[i - 524288u];
  else {
    // conv weights: idx = ((((cc*4+ocb)*9 + tap)*4 + rt)*64 + lane)*8 + e
    // oc = ocb*64 + rt*16 + (lane&15); ic = cc*32 + (lane>>4)*8 + e
    unsigned r = i - 589824u;
    unsigned e = r & 7u, l = (r >> 3) & 63u, rt = (r >> 9) & 3u;
    unsigned idx3 = r >> 11;
    unsigned tap = idx3 % 9u, q = idx3 / 9u;
    unsigned ocb = q & 3u, cc = q >> 2;
    unsigned oc = ocb * 64u + rt * 16u + (l & 15u);
    unsigned ic = cc * 32u + (l >> 4) * 8u + e;
    v = postw[(oc * 512u + ic) * 9u + tap];
  }
  wdst[i] = f2b(v);
}

// ================= shared GEMM: OUT[e][tok] += W[e][c] * X[tok][c] =================
__device__ __forceinline__ void gemm4x4(f32x4 acc[4][4], const unsigned short* __restrict__ wA,
                                        int Kw, int kw0, const unsigned short* sB, int strideB,
                                        int nK, int wid, int lane) {
  const int rA = lane & 15;
  const int kq = (lane >> 4) << 3;
  for (int ks = 0; ks < nK; ks += 32) {
    bf16x8 a[4];
#pragma unroll
    for (int rt = 0; rt < 4; ++rt)
      a[rt] = *reinterpret_cast<const bf16x8*>(wA + (wid * 64 + rt * 16 + rA) * Kw + kw0 + ks + kq);
#pragma unroll
    for (int ct = 0; ct < 4; ++ct) {
      bf16x8 bb = rd8(sB, ct * 16 + rA, strideB, ks + kq);
#pragma unroll
      for (int rt = 0; rt < 4; ++rt) acc[rt][ct] = MFMA16(a[rt], bb, acc[rt][ct]);
    }
  }
}

// stage 64 tokens x 128 channels of an NCHW fp32 input into swizzled bf16 LDS
__device__ __forceinline__ void stage128(unsigned short* sB, const float* __restrict__ src,
                                         int b, int Cin, int c0, int h0, int w0, int tid) {
#pragma unroll
  for (int it = 0; it < 4; ++it) {
    int p = tid + (it << 8);
    int c = p >> 3, r = p & 7;
    const float* g = src + ((long)(b * Cin + c0 + c) * 128 + (h0 + r)) * 128 + w0;
    float4 f0 = *reinterpret_cast<const float4*>(g);
    float4 f1 = *reinterpret_cast<const float4*>(g + 4);
    float v[8] = {f0.x, f0.y, f0.z, f0.w, f1.x, f1.y, f1.z, f1.w};
#pragma unroll
    for (int i = 0; i < 8; ++i) {
      int tok = (r << 3) + i;
      sB[tok * 128 + (c ^ ((tok & 7) << 3))] = f2b(v[i]);
    }
  }
}

__device__ __forceinline__ void epi_pe_lds(unsigned short* buf, const f32x4 acc[4][4],
                                           const float* peL, int wid, int lane) {
#pragma unroll
  for (int rt = 0; rt < 4; ++rt) {
    int e0 = wid * 64 + rt * 16 + ((lane >> 4) << 2);
#pragma unroll
    for (int ct = 0; ct < 4; ++ct) {
      int tok = ct * 16 + (lane & 15);
      int r = tok >> 3, cpx = tok & 7;
      const float* pe = (e0 < 128) ? (peL + r * 128 + e0) : (peL + (8 + cpx) * 128 + (e0 - 128));
      ushort4 pk;
      pk.x = f2b(acc[rt][ct][0] + pe[0]);
      pk.y = f2b(acc[rt][ct][1] + pe[1]);
      pk.z = f2b(acc[rt][ct][2] + pe[2]);
      pk.w = f2b(acc[rt][ct][3] + pe[3]);
      *reinterpret_cast<ushort4*>(buf + tok * 256 + (e0 ^ ((tok & 7) << 3))) = pk;
    }
  }
}

__device__ __forceinline__ void epi_bias_lds(unsigned short* buf, const f32x4 acc[4][4],
                                             const float* __restrict__ bias, int wid, int lane) {
#pragma unroll
  for (int rt = 0; rt < 4; ++rt) {
    int e0 = wid * 64 + rt * 16 + ((lane >> 4) << 2);
    float4 bs = *reinterpret_cast<const float4*>(bias + e0);
#pragma unroll
    for (int ct = 0; ct < 4; ++ct) {
      int tok = ct * 16 + (lane & 15);
      ushort4 pk;
      pk.x = f2b(acc[rt][ct][0] + bs.x);
      pk.y = f2b(acc[rt][ct][1] + bs.y);
      pk.z = f2b(acc[rt][ct][2] + bs.z);
      pk.w = f2b(acc[rt][ct][3] + bs.w);
      *reinterpret_cast<ushort4*>(buf + tok * 256 + (e0 ^ ((tok & 7) << 3))) = pk;
    }
  }
}

// y_t layout: [b][cc=ch/32][h][w][ch%32]
__device__ __forceinline__ void epi_global(unsigned short* __restrict__ y_t, const f32x4 acc[4][4],
                                           const float* __restrict__ bias, int chOff,
                                           int b, int h0, int w0, int wid, int lane) {
#pragma unroll
  for (int rt = 0; rt < 4; ++rt) {
    int e0 = wid * 64 + rt * 16 + ((lane >> 4) << 2);
    float4 bs = bias ? *reinterpret_cast<const float4*>(bias + e0) : make_float4(0.f, 0.f, 0.f, 0.f);
    int ch = chOff + e0;
#pragma unroll
    for (int ct = 0; ct < 4; ++ct) {
      int tok = ct * 16 + (lane & 15);
      int r = tok >> 3, cpx = tok & 7;
      long gy = ((((long)(b * 16 + (ch >> 5)) * 128 + (h0 + r)) * 128 + (w0 + cpx)) << 5) + (ch & 31);
      ushort4 pk;
      pk.x = f2b(acc[rt][ct][0] + bs.x);
      pk.y = f2b(acc[rt][ct][1] + bs.y);
      pk.z = f2b(acc[rt][ct][2] + bs.z);
      pk.w = f2b(acc[rt][ct][3] + bs.w);
      *reinterpret_cast<ushort4*>(y_t + gy) = pk;
    }
  }
}

// ================= fused: projections + PE + window MHA + out-proj + skip =================
__launch_bounds__(256, 1)
__global__ void k_attn(const float* __restrict__ x5, const float* __restrict__ d1,
                       const float* __restrict__ d2,
                       const unsigned short* __restrict__ w_qp, const unsigned short* __restrict__ w_kp,
                       const unsigned short* __restrict__ w_vp, const unsigned short* __restrict__ w_sp,
                       const unsigned short* __restrict__ w_in, const unsigned short* __restrict__ w_op,
                       const float* __restrict__ in_b, const float* __restrict__ out_b,
                       const float* __restrict__ peT, unsigned short* __restrict__ y_t) {
  extern __shared__ unsigned short sm[];
  unsigned short* bufQ = sm;              // [64][256]  q -> qh
  unsigned short* bufK = sm + 16384;      // [64][256]  k -> kh
  unsigned short* bufV = sm + 32768;      // [64][256]  v -> o
  unsigned short* bufX = sm + 49152;      // peL (float[16][128]) then vhT [256][64]
  unsigned short* bufI = sm + 65536;      // [64][128] staging; later P [64][64]
  float* peL = reinterpret_cast<float*>(bufX);

  const int tid = threadIdx.x;
  const int lane = tid & 63;
  const int wid = tid >> 6;
  const int kq = (lane >> 4) << 3;
  const int win = blockIdx.x;
  const int b = win >> 8, wh = (win >> 4) & 15, ww = win & 15;
  const int h0 = wh * 8, w0 = ww * 8;

  for (int i = tid; i < 2048; i += 256) {
    int rr = i >> 7, e = i & 127;
    int p = (rr < 8) ? (h0 + rr) : (w0 + rr - 8);
    peL[i] = peT[p * 128 + e];
  }

  const f32x4 vz = {0.f, 0.f, 0.f, 0.f};
  f32x4 accA[4][4], accB[4][4];

  // ---- q & skip (from d1) ----
#pragma unroll
  for (int i = 0; i < 4; ++i)
#pragma unroll
    for (int j = 0; j < 4; ++j) { accA[i][j] = vz; accB[i][j] = vz; }
  for (int c0 = 0; c0 < 256; c0 += 128) {
    __syncthreads();
    stage128(bufI, d1, b, 256, c0, h0, w0, tid);
    __syncthreads();
    gemm4x4(accA, w_qp, 256, c0, bufI, 128, 128, wid, lane);
    gemm4x4(accB, w_sp, 256, c0, bufI, 128, 128, wid, lane);
  }
  epi_pe_lds(bufQ, accA, peL, wid, lane);
  epi_global(y_t, accB, nullptr, 256, b, h0, w0, wid, lane);   // skip -> channels 256..511

  // ---- k (from x5, K=512) ----
#pragma unroll
  for (int i = 0; i < 4; ++i)
#pragma unroll
    for (int j = 0; j < 4; ++j) accA[i][j] = vz;
  for (int c0 = 0; c0 < 512; c0 += 128) {
    __syncthreads();
    stage128(bufI, x5, b, 512, c0, h0, w0, tid);
    __syncthreads();
    gemm4x4(accA, w_kp, 512, c0, bufI, 128, 128, wid, lane);
  }
  epi_pe_lds(bufK, accA, peL, wid, lane);

  // ---- v (from d2) ----
#pragma unroll
  for (int i = 0; i < 4; ++i)
#pragma unroll
    for (int j = 0; j < 4; ++j) accA[i][j] = vz;
  for (int c0 = 0; c0 < 256; c0 += 128) {
    __syncthreads();
    stage128(bufI, d2, b, 256, c0, h0, w0, tid);
    __syncthreads();
    gemm4x4(accA, w_vp, 256, c0, bufI, 128, 128, wid, lane);
  }
  epi_pe_lds(bufV, accA, peL, wid, lane);

  __syncthreads();

  // ---- qh ----
#pragma unroll
  for (int i = 0; i < 4; ++i)
#pragma unroll
    for (int j = 0; j < 4; ++j) accA[i][j] = vz;
  gemm4x4(accA, w_in, 256, 0, bufQ, 256, 256, wid, lane);
  __syncthreads();
  epi_bias_lds(bufQ, accA, in_b, wid, lane);

  // ---- kh ----
#pragma unroll
  for (int i = 0; i < 4; ++i)
#pragma unroll
    for (int j = 0; j < 4; ++j) accA[i][j] = vz;
  gemm4x4(accA, w_in + 65536, 256, 0, bufK, 256, 256, wid, lane);
  __syncthreads();
  epi_bias_lds(bufK, accA, in_b + 256, wid, lane);

  // ---- vh -> transposed vhT [ch][tok] in bufX ----
#pragma unroll
  for (int i = 0; i < 4; ++i)
#pragma unroll
    for (int j = 0; j < 4; ++j) accA[i][j] = vz;
  gemm4x4(accA, w_in + 131072, 256, 0, bufV, 256, 256, wid, lane);
  __syncthreads();
  {
    unsigned short* vhT = bufX;
#pragma unroll
    for (int rt = 0; rt < 4; ++rt) {
      int e0 = wid * 64 + rt * 16 + ((lane >> 4) << 2);
      float4 bs = *reinterpret_cast<const float4*>(in_b + 512 + e0);
      float bsv[4] = {bs.x, bs.y, bs.z, bs.w};
#pragma unroll
      for (int ct = 0; ct < 4; ++ct) {
        int tok = ct * 16 + (lane & 15);
#pragma unroll
        for (int j = 0; j < 4; ++j) {
          int ch = e0 + j;
          vhT[ch * 64 + (tok ^ ((ch & 7) << 3))] = f2b(accA[rt][ct][j] + bsv[j]);
        }
      }
    }
  }
  __syncthreads();

  // ---- per-head attention; o accumulates into bufV ----
  unsigned short* Pb = bufI;
  unsigned short* vhT = bufX;
  const float scl = 0.17677669529663687f;
  for (int hd = 0; hd < 8; ++hd) {
    f32x4 sv[4];
#pragma unroll
    for (int ct = 0; ct < 4; ++ct) sv[ct] = vz;
    {
      bf16x8 aq = rd8(bufQ, wid * 16 + (lane & 15), 256, hd * 32 + kq);
#pragma unroll
      for (int ct = 0; ct < 4; ++ct) {
        bf16x8 bk = rd8(bufK, ct * 16 + (lane & 15), 256, hd * 32 + kq);
        sv[ct] = MFMA16(aq, bk, sv[ct]);
      }
    }
    float pr[4][4];
#pragma unroll
    for (int j = 0; j < 4; ++j) {
      float mx = fmaxf(fmaxf(sv[0][j], sv[1][j]), fmaxf(sv[2][j], sv[3][j])) * scl;
#pragma unroll
      for (int m = 8; m >= 1; m >>= 1) mx = fmaxf(mx, __shfl_xor(mx, m));
      float sum = 0.f;
#pragma unroll
      for (int ct = 0; ct < 4; ++ct) {
        float p = __expf(sv[ct][j] * scl - mx);
        pr[ct][j] = p;
        sum += p;
      }
#pragma unroll
      for (int m = 8; m >= 1; m >>= 1) sum += __shfl_xor(sum, m);
      float inv = 1.f / sum;
#pragma unroll
      for (int ct = 0; ct < 4; ++ct) pr[ct][j] *= inv;
    }
#pragma unroll
    for (int ct = 0; ct < 4; ++ct)
#pragma unroll
      for (int j = 0; j < 4; ++j) {
        int q = wid * 16 + ((lane >> 4) << 2) + j;
        int kt = ct * 16 + (lane & 15);
        Pb[q * 64 + (kt ^ ((q & 7) << 3))] = f2b(pr[ct][j]);
      }
    f32x4 ov[2];
    ov[0] = vz; ov[1] = vz;
#pragma unroll
    for (int ks = 0; ks < 64; ks += 32) {
      bf16x8 bp = rd8(Pb, wid * 16 + (lane & 15), 64, ks + kq);
#pragma unroll
      for (int rt = 0; rt < 2; ++rt) {
        bf16x8 av = rd8(vhT, hd * 32 + rt * 16 + (lane & 15), 64, ks + kq);
        ov[rt] = MFMA16(av, bp, ov[rt]);
      }
    }
#pragma unroll
    for (int rt = 0; rt < 2; ++rt) {
      int ch0 = hd * 32 + rt * 16 + ((lane >> 4) << 2);
      int tok = wid * 16 + (lane & 15);
      ushort4 pk;
      pk.x = f2b(ov[rt][0]);
      pk.y = f2b(ov[rt][1]);
      pk.z = f2b(ov[rt][2]);
      pk.w = f2b(ov[rt][3]);
      *reinterpret_cast<ushort4*>(bufV + tok * 256 + (ch0 ^ ((tok & 7) << 3))) = pk;
    }
  }
  __syncthreads();

  // ---- out projection -> y_t channels 0..255 ----
#pragma unroll
  for (int i = 0; i < 4; ++i)
#pragma unroll
    for (int j = 0; j < 4; ++j) accA[i][j] = vz;
  gemm4x4(accA, w_op, 256, 0, bufV, 256, 256, wid, lane);
  epi_global(y_t, accA, out_b, 0, b, h0, w0, wid, lane);
}

// ================= conv 3x3 (512->256) implicit GEMM v4 =================
// block = 512 thr (8 waves), tile 64 oc x (16h x 32w); A+B both from LDS, dbuf'd.
// patch [18][34][32ic] swizzled; A fragment-packed, staged via global_load_lds.
// wave = 64 oc x (2h x 32w); acc[4 ocfrag][4: hh(2) x wseg(2)]
__device__ __forceinline__ void patch_load(const unsigned short* __restrict__ y_t,
                                           int b, int cc, int h0, int w0, int tid, uint4* pv) {
#pragma unroll
  for (int k = 0; k < 5; ++k) {
    int s = tid + (k << 9);
    uint4 v = make_uint4(0u, 0u, 0u, 0u);
    if (s < 2448) {
      int pr = (s * 482) >> 16;          // s / 136
      int rem = s - pr * 136;
      int pcpx = rem >> 2, g = rem & 3;
      int hh = h0 + pr - 1, wp = w0 + pcpx - 1;
      if ((unsigned)hh < 128u && (unsigned)wp < 128u)
        v = *reinterpret_cast<const uint4*>(
            y_t + ((((long)(b * 16 + cc) * 128 + hh) * 128 + wp) << 5) + (g << 3));
    }
    pv[k] = v;
  }
}

__device__ __forceinline__ void patch_store(unsigned short* buf, int tid, const uint4* pv) {
#pragma unroll
  for (int k = 0; k < 5; ++k) {
    int s = tid + (k << 9);
    if (s < 2448) {
      int pr = (s * 482) >> 16;
      int rem = s - pr * 136;
      int pcpx = rem >> 2, g = rem & 3;
      int pidx = pr * 34 + pcpx;
      *reinterpret_cast<uint4*>(buf + (pidx << 5) + ((g ^ ((pidx >> 1) & 3)) << 3)) = pv[k];
    }
  }
}

__device__ __forceinline__ void stage_A(const unsigned short* __restrict__ wA, int cc, int ocb,
                                        unsigned short* dstBase, int tid) {
  const unsigned short* src = wA + (size_t)(cc * 4 + ocb) * 18432 + tid * 8;
  unsigned short* dst = dstBase + tid * 8;
#pragma unroll
  for (int k = 0; k < 4; ++k) {
    __builtin_amdgcn_global_load_lds(
        (const __attribute__((address_space(1))) unsigned int*)(src + k * 4096),
        (__attribute__((address_space(3))) unsigned int*)(dst + k * 4096), 16, 0, 0);
  }
  if (tid < 256)
    __builtin_amdgcn_global_load_lds(
        (const __attribute__((address_space(1))) unsigned int*)(src + 16384),
        (__attribute__((address_space(3))) unsigned int*)(dst + 16384), 16, 0, 0);
}

__launch_bounds__(512, 2)
__global__ void k_conv(const unsigned short* __restrict__ y_t, const unsigned short* __restrict__ wc,
                       float* __restrict__ out) {
  extern __shared__ unsigned short cs[];
  unsigned short* Pb0 = cs;                 // 19584 sh
  unsigned short* Pb1 = cs + 19584;
  unsigned short* Ab0 = cs + 39168;         // 18432 sh
  unsigned short* Ab1 = cs + 57600;

  const int tid = threadIdx.x, lane = tid & 63, pxg = tid >> 6;
  const int gq = lane >> 4, l15 = lane & 15;
  const int bi = ((int)blockIdx.x & 7) * 128 + ((int)blockIdx.x >> 3);   // XCD-contiguous
  const int ocb = bi & 3, wb = (bi >> 2) & 3, hb = (bi >> 4) & 7, b = bi >> 7;
  const int h0 = hb * 16, w0 = wb * 32;

  const f32x4 vz = {0.f, 0.f, 0.f, 0.f};
  f32x4 acc[4][4];
#pragma unroll
  for (int rt = 0; rt < 4; ++rt)
#pragma unroll
    for (int ct = 0; ct < 4; ++ct) acc[rt][ct] = vz;

  uint4 pv[5];
  patch_load(y_t, b, 0, h0, w0, tid, pv);
  stage_A(wc, 0, ocb, Ab0, tid);
  patch_store(Pb0, tid, pv);
  __syncthreads();

#pragma unroll 1
  for (int cc = 0; cc < 16; ++cc) {
    const unsigned short* pb = (cc & 1) ? Pb1 : Pb0;
    const unsigned short* pa = (cc & 1) ? Ab1 : Ab0;
    if (cc < 15) {
      patch_load(y_t, b, cc + 1, h0, w0, tid, pv);          // issue early (T14)
      stage_A(wc, cc + 1, ocb, (cc & 1) ? Ab0 : Ab1, tid);  // async into other buffer
    }

#pragma unroll
    for (int kx = 0; kx < 3; ++kx) {
      bf16x8 bfr[4][2];
#pragma unroll
      for (int r = 0; r < 4; ++r)
#pragma unroll
        for (int ws = 0; ws < 2; ++ws) {
          int pidx = (pxg * 2 + r) * 34 + ws * 16 + l15 + kx;
          bfr[r][ws] = *reinterpret_cast<const bf16x8*>(
              pb + (pidx << 5) + ((gq ^ ((pidx >> 1) & 3)) << 3));
        }
      bf16x8 afr[3][4];
#pragma unroll
      for (int ky = 0; ky < 3; ++ky)
#pragma unroll
        for (int rt = 0; rt < 4; ++rt)
          afr[ky][rt] = *reinterpret_cast<const bf16x8*>(
              pa + (((ky * 3 + kx) * 4 + rt) << 9) + lane * 8);
#pragma unroll
      for (int ky = 0; ky < 3; ++ky)
#pragma unroll
        for (int ct = 0; ct < 4; ++ct) {
          int r = (ct >> 1) + ky, ws = ct & 1;
#pragma unroll
          for (int rt = 0; rt < 4; ++rt)
            acc[rt][ct] = MFMA16(afr[ky][rt], bfr[r][ws], acc[rt][ct]);
        }
    }

    if (cc < 15) patch_store((cc & 1) ? Pb0 : Pb1, tid, pv);  // write late (T14)
    __syncthreads();
  }

  // epilogue: oc = ocb*64 + rt*16 + gq*4 + j ; h = h0 + pxg*2 + (ct>>1); w = w0 + (ct&1)*16 + l15
#pragma unroll
  for (int rt = 0; rt < 4; ++rt) {
    int oc0 = ocb * 64 + rt * 16 + gq * 4;
#pragma unroll
    for (int ct = 0; ct < 4; ++ct) {
      int hh = h0 + pxg * 2 + (ct >> 1), wp = w0 + ((ct & 1) << 4) + l15;
      long base = (((long)(b * 256 + oc0)) * 128 + hh) * 128 + wp;
#pragma unroll
      for (int j = 0; j < 4; ++j) out[base + (long)j * 16384] = acc[rt][ct][j];
    }
  }
}

// ================= BN stats / finalize / apply =================
__global__ void k_stats(const float* __restrict__ out, float* __restrict__ sums) {
  __shared__ float s1[256], s2[256];
  int c = blockIdx.x, tid = threadIdx.x;
  float a1 = 0.f, a2 = 0.f;
  for (int bb = 0; bb < 8; ++bb) {
    const float4* p = reinterpret_cast<const float4*>(out + ((long)(bb * 256 + c)) * 16384);
    for (int i = tid; i < 4096; i += 256) {
      float4 v = p[i];
      a1 += v.x + v.y + v.z + v.w;
      a2 += v.x * v.x + v.y * v.y + v.z * v.z + v.w * v.w;
    }
  }
  s1[tid] = a1; s2[tid] = a2;
  __syncthreads();
  for (int s = 128; s > 0; s >>= 1) {
    if (tid < s) { s1[tid] += s1[tid + s]; s2[tid] += s2[tid + s]; }
    __syncthreads();
  }
  if (tid == 0) { sums[c] = s1[0]; sums[256 + c] = s2[0]; }
}

__global__ void k_final(const float* __restrict__ sums, const float* __restrict__ gamma,
                        const float* __restrict__ beta, float* __restrict__ sc) {
  int c = threadIdx.x;
  float mean = sums[c] * (1.f / 131072.f);
  float var = sums[256 + c] * (1.f / 131072.f) - mean * mean;
  float s = gamma[c] * rsqrtf(var + 1e-5f);
  sc[c] = s;
  sc[256 + c] = beta[c] - mean * s;
}

__global__ void k_apply(float* __restrict__ out, const float* __restrict__ sc) {
  const long n4 = 33554432 / 4;
  for (long i4 = (long)blockIdx.x * 256 + threadIdx.x; i4 < n4; i4 += (long)gridDim.x * 256) {
    float4 v = reinterpret_cast<float4*>(out)[i4];
    int c = (int)((i4 >> 12) & 255);
    float s = sc[c], sh = sc[256 + c];
    v.x = fmaxf(v.x * s + sh, 0.f);
    v.y = fmaxf(v.y * s + sh, 0.f);
    v.z = fmaxf(v.z * s + sh, 0.f);
    v.w = fmaxf(v.w * s + sh, 0.f);
    reinterpret_cast<float4*>(out)[i4] = v;
  }
}

// ================= launch =================
extern "C" void kernel_launch(void* const* d_in, const int* in_sizes, int n_in,
                              void* d_out, int out_size, void* d_ws, size_t ws_size,
                              hipStream_t stream) {
  const float* x5 = (const float*)d_in[0];
  const float* d1 = (const float*)d_in[1];
  const float* d2 = (const float*)d_in[2];
  const float* kp = (const float*)d_in[3];
  const float* qp = (const float*)d_in[4];
  const float* vp = (const float*)d_in[5];
  const float* spw = (const float*)d_in[6];
  const float* inw = (const float*)d_in[7];
  const float* inb = (const float*)d_in[8];
  const float* opw = (const float*)d_in[9];
  const float* opb = (const float*)d_in[10];
  const float* pw = (const float*)d_in[11];
  const float* gamma = (const float*)d_in[12];
  const float* beta = (const float*)d_in[13];

  if (ws_size < (size_t)WSO_TOTAL) {
    fprintf(stderr, "kernel_launch: ws too small: %zu < %u\n", ws_size, WSO_TOTAL);
    return;
  }

  char* ws = (char*)d_ws;
  float* peT = (float*)(ws + WSO_PE);
  unsigned short* w_qp = (unsigned short*)(ws + WSO_WQP);
  unsigned short* w_kp = (unsigned short*)(ws + WSO_WKP);
  unsigned short* w_vp = (unsigned short*)(ws + WSO_WVP);
  unsigned short* w_sp = (unsigned short*)(ws + WSO_WSP);
  unsigned short* w_in = (unsigned short*)(ws + WSO_WIN);
  unsigned short* w_op = (unsigned short*)(ws + WSO_WOP);
  unsigned short* w_c = (unsigned short*)(ws + WSO_WC);
  unsigned short* y_t = (unsigned short*)(ws + WSO_YT);
  float* sums = (float*)(ws + WSO_SUMS);
  float* sc = (float*)(ws + WSO_SC);

  hipFuncSetAttribute(reinterpret_cast<const void*>(k_attn),
                      hipFuncAttributeMaxDynamicSharedMemorySize, SMEM_ATTN);
  hipFuncSetAttribute(reinterpret_cast<const void*>(k_conv),
                      hipFuncAttributeMaxDynamicSharedMemorySize, SMEM_CONV);

  k_prep<<<6976, 256, 0, stream>>>(qp, kp, vp, spw, inw, opw, pw, peT, w_qp);
  k_attn<<<2048, 256, SMEM_ATTN, stream>>>(x5, d1, d2, w_qp, w_kp, w_vp, w_sp, w_in, w_op,
                                           inb, opb, peT, y_t);
  k_conv<<<1024, 512, SMEM_CONV, stream>>>(y_t, w_c, (float*)d_out);
  k_stats<<<256, 256, 0, stream>>>((const float*)d_out, sums);
  k_final<<<1, 256, 0, stream>>>(sums, gamma, beta, sc);
  k_apply<<<2048, 256, 0, stream>>>((float*)d_out, sc);
}

// Round 5
// 833.180 us; speedup vs baseline: 4.0194x; 1.3150x over previous
//
#include <hip/hip_runtime.h>
#include <cstdio>
#include <cmath>

typedef __attribute__((ext_vector_type(8))) short bf16x8;
typedef __attribute__((ext_vector_type(4))) float f32x4;

#define MFMA16(a, b, c) __builtin_amdgcn_mfma_f32_16x16x32_bf16((a), (b), (c), 0, 0, 0)

// ---------------- workspace layout (byte offsets) ----------------
#define WSO_PE    0u                          // float[128*128]
#define WSO_WQC   65536u                      // bf16 [256][256]  Wq@qp
#define WSO_WKC   (WSO_WQC + 131072u)         // bf16 [256][512]  Wk@kp
#define WSO_WVC   (WSO_WKC + 262144u)         // bf16 [256][256]  Wv@vp
#define WSO_WSP   (WSO_WVC + 131072u)         // bf16 [256][256]
#define WSO_WOP   (WSO_WSP + 131072u)         // bf16 [256][256]
#define WSO_WC    (WSO_WOP + 131072u)         // bf16 conv fragment-packed
#define WSO_TB    (WSO_WC + 2359296u)         // f32 [6][128][256] PE tables Aq,Bq,Ak,Bk,Av,Bv
#define WSO_QH    (WSO_TB + 786432u)          // bf16 [2048][8][64][32]
#define WSO_KH    (WSO_QH + 67108864u)        // bf16 [2048][8][64][32]
#define WSO_VT    (WSO_KH + 67108864u)        // bf16 [2048][8][32][64]  (transposed)
#define WSO_YT    (WSO_VT + 67108864u)        // bf16 [8][16cc][128][128][32c]
#define WSO_SUMS  (WSO_YT + 134217728u)       // float[512]
#define WSO_SC    (WSO_SUMS + 2048u)          // float[512]
#define WSO_TOTAL (WSO_SC + 2048u)

#define SMEM_CONV 152064

__device__ __forceinline__ unsigned short f2b(float x) {
  unsigned int u = __builtin_bit_cast(unsigned int, x);
  u += 0x7fffu + ((u >> 16) & 1u);
  return (unsigned short)(u >> 16);
}

__device__ __forceinline__ bf16x8 rd8(const unsigned short* s, int row, int stride, int k) {
  return *reinterpret_cast<const bf16x8*>(s + row * stride + (k ^ ((row & 7) << 3)));
}

// ================= prep: pe table + direct weight conversions =================
__global__ void k_prep(const float* __restrict__ spw, const float* __restrict__ opw,
                       const float* __restrict__ postw,
                       float* __restrict__ peT, unsigned short* __restrict__ wdst) {
  unsigned id = blockIdx.x * 256u + threadIdx.x;
  if (id < 16384u) {
    int p = id >> 7, j = id & 127;
    float div = expf(-9.210340371976184f * (float)(j & ~1) * (1.0f / 128.0f));
    float ang = (float)p * div;
    peT[id] = (j & 1) ? cosf(ang) : sinf(ang);
    return;
  }
  unsigned i = id - 16384u;
  if (i >= 1310720u) return;
  float v;
  if (i < 65536u)            v = spw[i];
  else if (i < 131072u)      v = opw[i - 65536u];
  else {
    // conv weights: idx = ((((cc*4+ocb)*9 + tap)*4 + rt)*64 + lane)*8 + e
    unsigned r = i - 131072u;
    unsigned e = r & 7u, l = (r >> 3) & 63u, rt = (r >> 9) & 3u;
    unsigned idx3 = r >> 11;
    unsigned tap = idx3 % 9u, q = idx3 / 9u;
    unsigned ocb = q & 3u, cc = q >> 2;
    unsigned oc = ocb * 64u + rt * 16u + (l & 15u);
    unsigned ic = cc * 32u + (l >> 4) * 8u + e;
    v = postw[(oc * 512u + ic) * 9u + tap];
  }
  wdst[i] = f2b(v);
}

// ================= fold: combined weights + PE tables =================
__global__ void k_fold(const float* __restrict__ qpw, const float* __restrict__ kpw,
                       const float* __restrict__ vpw, const float* __restrict__ inw,
                       const float* __restrict__ inb, const float* __restrict__ peT,
                       unsigned short* __restrict__ wqc, unsigned short* __restrict__ wkc,
                       unsigned short* __restrict__ wvc, float* __restrict__ tb) {
  __shared__ float wrow[256];
  const int tid = threadIdx.x, bid = blockIdx.x;
  if (bid < 768) {
    int m = bid >> 8;                 // 0 q, 1 k, 2 v
    int e2 = bid & 255;
    wrow[tid] = inw[(m * 256 + e2) * 256 + tid];
    __syncthreads();
    if (m == 1) {
      float a0 = 0.f, a1 = 0.f;
      for (int e = 0; e < 256; ++e) {
        float s = wrow[e];
        a0 = fmaf(s, kpw[e * 512 + tid], a0);
        a1 = fmaf(s, kpw[e * 512 + 256 + tid], a1);
      }
      wkc[e2 * 512 + tid] = f2b(a0);
      wkc[e2 * 512 + 256 + tid] = f2b(a1);
    } else {
      const float* pw = (m == 0) ? qpw : vpw;
      float a0 = 0.f;
      for (int e = 0; e < 256; ++e) a0 = fmaf(wrow[e], pw[e * 256 + tid], a0);
      unsigned short* dst = (m == 0) ? wqc : wvc;
      dst[e2 * 256 + tid] = f2b(a0);
    }
  } else {
    int r = bid - 768;
    int t = r >> 7, p = r & 127;      // t: 0 Aq,1 Bq,2 Ak,3 Bk,4 Av,5 Bv
    if (tid < 128) wrow[tid] = peT[p * 128 + tid];
    __syncthreads();
    int woff = (t >> 1) * 256, joff = (t & 1) * 128;
    float acc = (t & 1) ? 0.f : inb[woff + tid];
    const float* wr = inw + (size_t)(woff + tid) * 256 + joff;
    for (int j = 0; j < 128; ++j) acc = fmaf(wrow[j], wr[j], acc);
    tb[t * 32768 + p * 256 + tid] = acc;
  }
}

// ================= shared GEMM: OUT[e][tok] += W[e][c] * X[tok][c] =================
__device__ __forceinline__ void gemm4x4(f32x4 acc[4][4], const unsigned short* __restrict__ wA,
                                        int Kw, int kw0, const unsigned short* sB, int strideB,
                                        int nK, int wid, int lane) {
  const int rA = lane & 15;
  const int kq = (lane >> 4) << 3;
  for (int ks = 0; ks < nK; ks += 32) {
    bf16x8 a[4];
#pragma unroll
    for (int rt = 0; rt < 4; ++rt)
      a[rt] = *reinterpret_cast<const bf16x8*>(wA + (wid * 64 + rt * 16 + rA) * Kw + kw0 + ks + kq);
#pragma unroll
    for (int ct = 0; ct < 4; ++ct) {
      bf16x8 bb = rd8(sB, ct * 16 + rA, strideB, ks + kq);
#pragma unroll
      for (int rt = 0; rt < 4; ++rt) acc[rt][ct] = MFMA16(a[rt], bb, acc[rt][ct]);
    }
  }
}

// stage 64 tokens x 128 channels, NCHW fp32 -> swizzled bf16 LDS.
// thread = (tok = tid&63, cb = (tid>>6)*8): one ds_write_b128 per chunk, conflict-free.
__device__ __forceinline__ void stage128(unsigned short* sB, const float* __restrict__ src,
                                         int b, int Cin, int c0, int h0, int w0, int tid) {
  const int tok = tid & 63;
  const long base = ((long)(b * Cin + c0) << 14) + (h0 + (tok >> 3)) * 128 + w0 + (tok & 7);
  const int cb = (tid >> 6) << 3;
#pragma unroll
  for (int it = 0; it < 4; ++it) {
    const int c = cb + (it << 5);
    float v[8];
#pragma unroll
    for (int u = 0; u < 8; ++u) v[u] = src[base + ((long)(c + u) << 14)];
    bf16x8 pk;
#pragma unroll
    for (int u = 0; u < 8; ++u) ((unsigned short*)&pk)[u] = f2b(v[u]);
    *reinterpret_cast<bf16x8*>(&sB[(tok << 7) + (c ^ ((tok & 7) << 3))]) = pk;
  }
}

// epilogue -> head-major qh/kh [hd][tok][32ch] with PE-table add
__device__ __forceinline__ void epi_qk(unsigned short* __restrict__ dst, const f32x4 acc[4][4],
                                       const float* __restrict__ At, const float* __restrict__ Bt,
                                       int h0, int w0, int wid, int lane) {
  const int gq = lane >> 4, l15 = lane & 15;
#pragma unroll
  for (int rt = 0; rt < 4; ++rt) {
    int e0 = wid * 64 + rt * 16 + gq * 4;
    int hd = e0 >> 5, chb = e0 & 31;
#pragma unroll
    for (int ct = 0; ct < 4; ++ct) {
      int tok = ct * 16 + l15;
      float4 av = *reinterpret_cast<const float4*>(At + (h0 + (tok >> 3)) * 256 + e0);
      float4 bv = *reinterpret_cast<const float4*>(Bt + (w0 + (tok & 7)) * 256 + e0);
      ushort4 pk;
      pk.x = f2b(acc[rt][ct][0] + av.x + bv.x);
      pk.y = f2b(acc[rt][ct][1] + av.y + bv.y);
      pk.z = f2b(acc[rt][ct][2] + av.z + bv.z);
      pk.w = f2b(acc[rt][ct][3] + av.w + bv.w);
      *reinterpret_cast<ushort4*>(dst + ((hd * 64 + tok) << 5) + chb) = pk;
    }
  }
}

// epilogue -> transposed vhT [hd][32ch][64tok] with PE-table add
__device__ __forceinline__ void epi_vT(unsigned short* __restrict__ dst, const f32x4 acc[4][4],
                                       const float* __restrict__ At, const float* __restrict__ Bt,
                                       int h0, int w0, int wid, int lane) {
  const int gq = lane >> 4, l15 = lane & 15;
#pragma unroll
  for (int rt = 0; rt < 4; ++rt) {
    int e0 = wid * 64 + rt * 16 + gq * 4;
    int hd = e0 >> 5, chb = e0 & 31;
#pragma unroll
    for (int ct = 0; ct < 4; ++ct) {
      int tok = ct * 16 + l15;
      float4 av = *reinterpret_cast<const float4*>(At + (h0 + (tok >> 3)) * 256 + e0);
      float4 bv = *reinterpret_cast<const float4*>(Bt + (w0 + (tok & 7)) * 256 + e0);
#pragma unroll
      for (int j = 0; j < 4; ++j) {
        float v = acc[rt][ct][j] + ((const float*)&av)[j] + ((const float*)&bv)[j];
        dst[((hd * 32 + chb + j) << 6) + tok] = f2b(v);
      }
    }
  }
}

// y_t layout: [b][cc=ch/32][h][w][ch%32]
__device__ __forceinline__ void epi_global(unsigned short* __restrict__ y_t, const f32x4 acc[4][4],
                                           const float* __restrict__ bias, int chOff,
                                           int b, int h0, int w0, int wid, int lane) {
#pragma unroll
  for (int rt = 0; rt < 4; ++rt) {
    int e0 = wid * 64 + rt * 16 + ((lane >> 4) << 2);
    float4 bs = bias ? *reinterpret_cast<const float4*>(bias + e0) : make_float4(0.f, 0.f, 0.f, 0.f);
    int ch = chOff + e0;
#pragma unroll
    for (int ct = 0; ct < 4; ++ct) {
      int tok = ct * 16 + (lane & 15);
      int r = tok >> 3, cpx = tok & 7;
      long gy = ((((long)(b * 16 + (ch >> 5)) * 128 + (h0 + r)) * 128 + (w0 + cpx)) << 5) + (ch & 31);
      ushort4 pk;
      pk.x = f2b(acc[rt][ct][0] + bs.x);
      pk.y = f2b(acc[rt][ct][1] + bs.y);
      pk.z = f2b(acc[rt][ct][2] + bs.z);
      pk.w = f2b(acc[rt][ct][3] + bs.w);
      *reinterpret_cast<ushort4*>(y_t + gy) = pk;
    }
  }
}

// ================= projections (folded): qh/kh/vhT/skip =================
__launch_bounds__(256, 2)
__global__ void k_proj(const float* __restrict__ x5, const float* __restrict__ d1,
                       const float* __restrict__ d2,
                       const unsigned short* __restrict__ wqc, const unsigned short* __restrict__ wkc,
                       const unsigned short* __restrict__ wvc, const unsigned short* __restrict__ wsp,
                       const float* __restrict__ tb,
                       unsigned short* __restrict__ qh, unsigned short* __restrict__ kh,
                       unsigned short* __restrict__ vt, unsigned short* __restrict__ y_t) {
  __shared__ unsigned short sB[8192];
  const int tid = threadIdx.x, lane = tid & 63, wid = tid >> 6;
  const int bid = blockIdx.x;
  const int win = ((bid & 7) << 8) | (bid >> 3);     // XCD-contiguous windows
  const int b = win >> 8, wh = (win >> 4) & 15, ww = win & 15;
  const int h0 = wh * 8, w0 = ww * 8;

  const f32x4 vz = {0.f, 0.f, 0.f, 0.f};
  f32x4 accA[4][4], accB[4][4];

  // ---- q + skip (from d1) ----
#pragma unroll
  for (int i = 0; i < 4; ++i)
#pragma unroll
    for (int j = 0; j < 4; ++j) { accA[i][j] = vz; accB[i][j] = vz; }
  for (int c0 = 0; c0 < 256; c0 += 128) {
    __syncthreads();
    stage128(sB, d1, b, 256, c0, h0, w0, tid);
    __syncthreads();
    gemm4x4(accA, wqc, 256, c0, sB, 128, 128, wid, lane);
    gemm4x4(accB, wsp, 256, c0, sB, 128, 128, wid, lane);
  }
  epi_qk(qh + ((size_t)win << 14), accA, tb, tb + 32768, h0, w0, wid, lane);
  epi_global(y_t, accB, nullptr, 256, b, h0, w0, wid, lane);

  // ---- k (from x5, K=512) ----
#pragma unroll
  for (int i = 0; i < 4; ++i)
#pragma unroll
    for (int j = 0; j < 4; ++j) accA[i][j] = vz;
  for (int c0 = 0; c0 < 512; c0 += 128) {
    __syncthreads();
    stage128(sB, x5, b, 512, c0, h0, w0, tid);
    __syncthreads();
    gemm4x4(accA, wkc, 512, c0, sB, 128, 128, wid, lane);
  }
  epi_qk(kh + ((size_t)win << 14), accA, tb + 65536, tb + 98304, h0, w0, wid, lane);

  // ---- v (from d2) ----
#pragma unroll
  for (int i = 0; i < 4; ++i)
#pragma unroll
    for (int j = 0; j < 4; ++j) accA[i][j] = vz;
  for (int c0 = 0; c0 < 256; c0 += 128) {
    __syncthreads();
    stage128(sB, d2, b, 256, c0, h0, w0, tid);
    __syncthreads();
    gemm4x4(accA, wvc, 256, c0, sB, 128, 128, wid, lane);
  }
  epi_vT(vt + ((size_t)win << 14), accA, tb + 131072, tb + 163840, h0, w0, wid, lane);
}

// ================= window attention + out-proj =================
__launch_bounds__(256, 3)
__global__ void k_wattn(const unsigned short* __restrict__ qh, const unsigned short* __restrict__ kh,
                        const unsigned short* __restrict__ vt, const unsigned short* __restrict__ wop,
                        const float* __restrict__ out_b, unsigned short* __restrict__ y_t) {
  __shared__ unsigned short Pb[4096];       // P [64][64] swizzled
  __shared__ unsigned short bufO[16384];    // O [64][256] swizzled
  const int tid = threadIdx.x, lane = tid & 63, wid = tid >> 6;
  const int gq = lane >> 4, l15 = lane & 15, kq = gq << 3;
  const int bid = blockIdx.x;
  const int win = ((bid & 7) << 8) | (bid >> 3);
  const int b = win >> 8, wh = (win >> 4) & 15, ww = win & 15;
  const int h0 = wh * 8, w0 = ww * 8;

  const unsigned short* qw = qh + ((size_t)win << 14);
  const unsigned short* kw = kh + ((size_t)win << 14);
  const unsigned short* vw = vt + ((size_t)win << 14);

  const f32x4 vz = {0.f, 0.f, 0.f, 0.f};
  const float scl = 0.17677669529663687f;   // 1/sqrt(32)
  f32x4 o0[8], o1[8];
#pragma unroll
  for (int h = 0; h < 8; ++h) { o0[h] = vz; o1[h] = vz; }

#pragma unroll
  for (int hd = 0; hd < 8; ++hd) {
    const unsigned short* qb = qw + (hd << 11);
    const unsigned short* kb = kw + (hd << 11);
    const unsigned short* vb = vw + (hd << 11);
    // S = Q K^T (K=32: one k-step); wave owns q rows wid*16..+15
    bf16x8 aq = *reinterpret_cast<const bf16x8*>(qb + ((wid * 16 + l15) << 5) + kq);
    f32x4 sv[4];
#pragma unroll
    for (int ct = 0; ct < 4; ++ct) {
      bf16x8 bk = *reinterpret_cast<const bf16x8*>(kb + ((ct * 16 + l15) << 5) + kq);
      sv[ct] = MFMA16(aq, bk, vz);
    }
    // softmax over 64 k per q-row
    float pr[4][4];
#pragma unroll
    for (int j = 0; j < 4; ++j) {
      float mx = fmaxf(fmaxf(sv[0][j], sv[1][j]), fmaxf(sv[2][j], sv[3][j])) * scl;
#pragma unroll
      for (int m = 8; m >= 1; m >>= 1) mx = fmaxf(mx, __shfl_xor(mx, m));
      float sum = 0.f;
#pragma unroll
      for (int ct = 0; ct < 4; ++ct) {
        float p = __expf(sv[ct][j] * scl - mx);
        pr[ct][j] = p;
        sum += p;
      }
#pragma unroll
      for (int m = 8; m >= 1; m >>= 1) sum += __shfl_xor(sum, m);
      float inv = 1.f / sum;
#pragma unroll
      for (int ct = 0; ct < 4; ++ct) pr[ct][j] *= inv;
    }
    // P -> LDS (per-wave-private rows)
#pragma unroll
    for (int ct = 0; ct < 4; ++ct)
#pragma unroll
      for (int j = 0; j < 4; ++j) {
        int q = wid * 16 + gq * 4 + j;
        int kt = ct * 16 + l15;
        Pb[q * 64 + (kt ^ ((q & 7) << 3))] = f2b(pr[ct][j]);
      }
    // PV: O^T[ch][q] += V^T[ch][k] P[q][k]
#pragma unroll
    for (int ks = 0; ks < 64; ks += 32) {
      bf16x8 bp = rd8(Pb, wid * 16 + l15, 64, ks + kq);
      bf16x8 a0 = *reinterpret_cast<const bf16x8*>(vb + (l15 << 6) + ks + kq);
      bf16x8 a1 = *reinterpret_cast<const bf16x8*>(vb + ((16 + l15) << 6) + ks + kq);
      o0[hd] = MFMA16(a0, bp, o0[hd]);
      o1[hd] = MFMA16(a1, bp, o1[hd]);
    }
  }

  // O -> bufO [tok][256] swizzled
  {
    int tok = wid * 16 + l15;
    int sw = (tok & 7) << 3;
#pragma unroll
    for (int hd = 0; hd < 8; ++hd)
#pragma unroll
      for (int rt = 0; rt < 2; ++rt) {
        f32x4 ov = rt ? o1[hd] : o0[hd];
        int ch0 = hd * 32 + rt * 16 + gq * 4;
        ushort4 pk;
        pk.x = f2b(ov[0]); pk.y = f2b(ov[1]); pk.z = f2b(ov[2]); pk.w = f2b(ov[3]);
        *reinterpret_cast<ushort4*>(&bufO[tok * 256 + (ch0 ^ sw)]) = pk;
      }
  }
  __syncthreads();

  // out-proj -> y_t ch 0..255
  f32x4 accA[4][4];
#pragma unroll
  for (int i = 0; i < 4; ++i)
#pragma unroll
    for (int j = 0; j < 4; ++j) accA[i][j] = vz;
  gemm4x4(accA, wop, 256, 0, bufO, 256, 256, wid, lane);
  epi_global(y_t, accA, out_b, 0, b, h0, w0, wid, lane);
}

// ================= conv 3x3 (512->256) implicit GEMM (unchanged v4) =================
__device__ __forceinline__ void patch_load(const unsigned short* __restrict__ y_t,
                                           int b, int cc, int h0, int w0, int tid, uint4* pv) {
#pragma unroll
  for (int k = 0; k < 5; ++k) {
    int s = tid + (k << 9);
    uint4 v = make_uint4(0u, 0u, 0u, 0u);
    if (s < 2448) {
      int pr = (s * 482) >> 16;
      int rem = s - pr * 136;
      int pcpx = rem >> 2, g = rem & 3;
      int hh = h0 + pr - 1, wp = w0 + pcpx - 1;
      if ((unsigned)hh < 128u && (unsigned)wp < 128u)
        v = *reinterpret_cast<const uint4*>(
            y_t + ((((long)(b * 16 + cc) * 128 + hh) * 128 + wp) << 5) + (g << 3));
    }
    pv[k] = v;
  }
}

__device__ __forceinline__ void patch_store(unsigned short* buf, int tid, const uint4* pv) {
#pragma unroll
  for (int k = 0; k < 5; ++k) {
    int s = tid + (k << 9);
    if (s < 2448) {
      int pr = (s * 482) >> 16;
      int rem = s - pr * 136;
      int pcpx = rem >> 2, g = rem & 3;
      int pidx = pr * 34 + pcpx;
      *reinterpret_cast<uint4*>(buf + (pidx << 5) + ((g ^ ((pidx >> 1) & 3)) << 3)) = pv[k];
    }
  }
}

__device__ __forceinline__ void stage_A(const unsigned short* __restrict__ wA, int cc, int ocb,
                                        unsigned short* dstBase, int tid) {
  const unsigned short* src = wA + (size_t)(cc * 4 + ocb) * 18432 + tid * 8;
  unsigned short* dst = dstBase + tid * 8;
#pragma unroll
  for (int k = 0; k < 4; ++k) {
    __builtin_amdgcn_global_load_lds(
        (const __attribute__((address_space(1))) unsigned int*)(src + k * 4096),
        (__attribute__((address_space(3))) unsigned int*)(dst + k * 4096), 16, 0, 0);
  }
  if (tid < 256)
    __builtin_amdgcn_global_load_lds(
        (const __attribute__((address_space(1))) unsigned int*)(src + 16384),
        (__attribute__((address_space(3))) unsigned int*)(dst + 16384), 16, 0, 0);
}

__launch_bounds__(512, 2)
__global__ void k_conv(const unsigned short* __restrict__ y_t, const unsigned short* __restrict__ wc,
                       float* __restrict__ out) {
  extern __shared__ unsigned short cs[];
  unsigned short* Pb0 = cs;
  unsigned short* Pb1 = cs + 19584;
  unsigned short* Ab0 = cs + 39168;
  unsigned short* Ab1 = cs + 57600;

  const int tid = threadIdx.x, lane = tid & 63, pxg = tid >> 6;
  const int gq = lane >> 4, l15 = lane & 15;
  const int bi = ((int)blockIdx.x & 7) * 128 + ((int)blockIdx.x >> 3);
  const int ocb = bi & 3, wb = (bi >> 2) & 3, hb = (bi >> 4) & 7, b = bi >> 7;
  const int h0 = hb * 16, w0 = wb * 32;

  const f32x4 vz = {0.f, 0.f, 0.f, 0.f};
  f32x4 acc[4][4];
#pragma unroll
  for (int rt = 0; rt < 4; ++rt)
#pragma unroll
    for (int ct = 0; ct < 4; ++ct) acc[rt][ct] = vz;

  uint4 pv[5];
  patch_load(y_t, b, 0, h0, w0, tid, pv);
  stage_A(wc, 0, ocb, Ab0, tid);
  patch_store(Pb0, tid, pv);
  __syncthreads();

#pragma unroll 1
  for (int cc = 0; cc < 16; ++cc) {
    const unsigned short* pb = (cc & 1) ? Pb1 : Pb0;
    const unsigned short* pa = (cc & 1) ? Ab1 : Ab0;
    if (cc < 15) {
      patch_load(y_t, b, cc + 1, h0, w0, tid, pv);
      stage_A(wc, cc + 1, ocb, (cc & 1) ? Ab0 : Ab1, tid);
    }

#pragma unroll
    for (int kx = 0; kx < 3; ++kx) {
      bf16x8 bfr[4][2];
#pragma unroll
      for (int r = 0; r < 4; ++r)
#pragma unroll
        for (int ws = 0; ws < 2; ++ws) {
          int pidx = (pxg * 2 + r) * 34 + ws * 16 + l15 + kx;
          bfr[r][ws] = *reinterpret_cast<const bf16x8*>(
              pb + (pidx << 5) + ((gq ^ ((pidx >> 1) & 3)) << 3));
        }
      bf16x8 afr[3][4];
#pragma unroll
      for (int ky = 0; ky < 3; ++ky)
#pragma unroll
        for (int rt = 0; rt < 4; ++rt)
          afr[ky][rt] = *reinterpret_cast<const bf16x8*>(
              pa + (((ky * 3 + kx) * 4 + rt) << 9) + lane * 8);
#pragma unroll
      for (int ky = 0; ky < 3; ++ky)
#pragma unroll
        for (int ct = 0; ct < 4; ++ct) {
          int r = (ct >> 1) + ky, ws = ct & 1;
#pragma unroll
          for (int rt = 0; rt < 4; ++rt)
            acc[rt][ct] = MFMA16(afr[ky][rt], bfr[r][ws], acc[rt][ct]);
        }
    }

    if (cc < 15) patch_store((cc & 1) ? Pb0 : Pb1, tid, pv);
    __syncthreads();
  }

#pragma unroll
  for (int rt = 0; rt < 4; ++rt) {
    int oc0 = ocb * 64 + rt * 16 + gq * 4;
#pragma unroll
    for (int ct = 0; ct < 4; ++ct) {
      int hh = h0 + pxg * 2 + (ct >> 1), wp = w0 + ((ct & 1) << 4) + l15;
      long base = (((long)(b * 256 + oc0)) * 128 + hh) * 128 + wp;
#pragma unroll
      for (int j = 0; j < 4; ++j) out[base + (long)j * 16384] = acc[rt][ct][j];
    }
  }
}

// ================= BN stats / finalize / apply =================
__global__ void k_stats(const float* __restrict__ out, float* __restrict__ sums) {
  __shared__ float s1[256], s2[256];
  int c = blockIdx.x, tid = threadIdx.x;
  float a1 = 0.f, a2 = 0.f;
  for (int bb = 0; bb < 8; ++bb) {
    const float4* p = reinterpret_cast<const float4*>(out + ((long)(bb * 256 + c)) * 16384);
    for (int i = tid; i < 4096; i += 256) {
      float4 v = p[i];
      a1 += v.x + v.y + v.z + v.w;
      a2 += v.x * v.x + v.y * v.y + v.z * v.z + v.w * v.w;
    }
  }
  s1[tid] = a1; s2[tid] = a2;
  __syncthreads();
  for (int s = 128; s > 0; s >>= 1) {
    if (tid < s) { s1[tid] += s1[tid + s]; s2[tid] += s2[tid + s]; }
    __syncthreads();
  }
  if (tid == 0) { sums[c] = s1[0]; sums[256 + c] = s2[0]; }
}

__global__ void k_final(const float* __restrict__ sums, const float* __restrict__ gamma,
                        const float* __restrict__ beta, float* __restrict__ sc) {
  int c = threadIdx.x;
  float mean = sums[c] * (1.f / 131072.f);
  float var = sums[256 + c] * (1.f / 131072.f) - mean * mean;
  float s = gamma[c] * rsqrtf(var + 1e-5f);
  sc[c] = s;
  sc[256 + c] = beta[c] - mean * s;
}

__global__ void k_apply(float* __restrict__ out, const float* __restrict__ sc) {
  const long n4 = 33554432 / 4;
  for (long i4 = (long)blockIdx.x * 256 + threadIdx.x; i4 < n4; i4 += (long)gridDim.x * 256) {
    float4 v = reinterpret_cast<float4*>(out)[i4];
    int c = (int)((i4 >> 12) & 255);
    float s = sc[c], sh = sc[256 + c];
    v.x = fmaxf(v.x * s + sh, 0.f);
    v.y = fmaxf(v.y * s + sh, 0.f);
    v.z = fmaxf(v.z * s + sh, 0.f);
    v.w = fmaxf(v.w * s + sh, 0.f);
    reinterpret_cast<float4*>(out)[i4] = v;
  }
}

// ================= launch =================
extern "C" void kernel_launch(void* const* d_in, const int* in_sizes, int n_in,
                              void* d_out, int out_size, void* d_ws, size_t ws_size,
                              hipStream_t stream) {
  const float* x5 = (const float*)d_in[0];
  const float* d1 = (const float*)d_in[1];
  const float* d2 = (const float*)d_in[2];
  const float* kp = (const float*)d_in[3];
  const float* qp = (const float*)d_in[4];
  const float* vp = (const float*)d_in[5];
  const float* spw = (const float*)d_in[6];
  const float* inw = (const float*)d_in[7];
  const float* inb = (const float*)d_in[8];
  const float* opw = (const float*)d_in[9];
  const float* opb = (const float*)d_in[10];
  const float* pw = (const float*)d_in[11];
  const float* gamma = (const float*)d_in[12];
  const float* beta = (const float*)d_in[13];

  if (ws_size < (size_t)WSO_TOTAL) {
    fprintf(stderr, "kernel_launch: ws too small: %zu < %u\n", ws_size, WSO_TOTAL);
    return;
  }

  char* ws = (char*)d_ws;
  float* peT = (float*)(ws + WSO_PE);
  unsigned short* w_qc = (unsigned short*)(ws + WSO_WQC);
  unsigned short* w_kc = (unsigned short*)(ws + WSO_WKC);
  unsigned short* w_vc = (unsigned short*)(ws + WSO_WVC);
  unsigned short* w_sp = (unsigned short*)(ws + WSO_WSP);
  unsigned short* w_op = (unsigned short*)(ws + WSO_WOP);
  unsigned short* w_c = (unsigned short*)(ws + WSO_WC);
  float* tb = (float*)(ws + WSO_TB);
  unsigned short* qh = (unsigned short*)(ws + WSO_QH);
  unsigned short* kh = (unsigned short*)(ws + WSO_KH);
  unsigned short* vt = (unsigned short*)(ws + WSO_VT);
  unsigned short* y_t = (unsigned short*)(ws + WSO_YT);
  float* sums = (float*)(ws + WSO_SUMS);
  float* sc = (float*)(ws + WSO_SC);

  hipFuncSetAttribute(reinterpret_cast<const void*>(k_conv),
                      hipFuncAttributeMaxDynamicSharedMemorySize, SMEM_CONV);

  k_prep<<<5184, 256, 0, stream>>>(spw, opw, pw, peT, w_sp);
  k_fold<<<1536, 256, 0, stream>>>(qp, kp, vp, inw, inb, peT, w_qc, w_kc, w_vc, tb);
  k_proj<<<2048, 256, 0, stream>>>(x5, d1, d2, w_qc, w_kc, w_vc, w_sp, tb, qh, kh, vt, y_t);
  k_wattn<<<2048, 256, 0, stream>>>(qh, kh, vt, w_op, opb, y_t);
  k_conv<<<1024, 512, SMEM_CONV, stream>>>(y_t, w_c, (float*)d_out);
  k_stats<<<256, 256, 0, stream>>>((const float*)d_out, sums);
  k_final<<<1, 256, 0, stream>>>(sums, gamma, beta, sc);
  k_apply<<<2048, 256, 0, stream>>>((float*)d_out, sc);
}